// Round 11
// baseline (470.340 us; speedup 1.0000x reference)
//
#include <hip/hip_runtime.h>
#include <hip/hip_fp16.h>
#include <math.h>

constexpr int NN  = 50000;   // nodes
constexpr int EE  = 800000;  // edges
constexpr int INF_ = 256;    // input feat
constexpr int HF  = 128;     // hidden
constexpr int CC  = 50;      // classes
constexpr long NH = (long)NN * HF;
constexpr int NSL = 32;          // edge slices (preprocessing)
constexpr int ESL = EE / NSL;    // 25000 edges per slice
constexpr int CHK = 12500;       // nodes per chunk (4 chunks), 50KB LDS
#define EPSV 1e-5f

enum { EPI_RELU = 0, EPI_NONE = 1, EPI_BN = 2, EPI_BN_RES = 3 };
enum { H16_NONE = 0, H16_RAW = 1, H16_SCALED = 2 };

typedef __attribute__((ext_vector_type(4))) float f32x4;
typedef __attribute__((ext_vector_type(8))) short bf16x8;

__device__ __forceinline__ ushort f2bf(float f) {
  union { float f; unsigned u; } v; v.f = f;
  unsigned r = (v.u + 0x7fffu + ((v.u >> 16) & 1u)) >> 16;  // RNE
  return (ushort)r;
}
__device__ __forceinline__ float bf2f(ushort u) {
  union { unsigned u; float f; } v; v.u = ((unsigned)u) << 16;
  return v.f;
}

// ---------------- graph preprocessing (atomic-free: LDS histograms) ----------------

__global__ __launch_bounds__(256) void count_partial_kernel(
    const int4* __restrict__ keys4, unsigned* __restrict__ partials) {
  __shared__ unsigned cnt[CHK];
  const int chunk = blockIdx.x & 3;
  const int sl = blockIdx.x >> 2;
  for (int i = threadIdx.x; i < CHK; i += 256) cnt[i] = 0;
  __syncthreads();
  const int base4 = sl * (ESL / 4);
  const int lo = chunk * CHK;
  for (int i = threadIdx.x; i < ESL / 4; i += 256) {
    int4 k = keys4[base4 + i];
    int a;
    a = k.x - lo; if ((unsigned)a < (unsigned)CHK) atomicAdd(&cnt[a], 1u);
    a = k.y - lo; if ((unsigned)a < (unsigned)CHK) atomicAdd(&cnt[a], 1u);
    a = k.z - lo; if ((unsigned)a < (unsigned)CHK) atomicAdd(&cnt[a], 1u);
    a = k.w - lo; if ((unsigned)a < (unsigned)CHK) atomicAdd(&cnt[a], 1u);
  }
  __syncthreads();
  unsigned* p = partials + (long)sl * NN + lo;
  for (int i = threadIdx.x; i < CHK; i += 256) p[i] = cnt[i];
}

__global__ __launch_bounds__(256) void reduce_deg_kernel(
    const unsigned* __restrict__ pd, const unsigned* __restrict__ ps,
    int* __restrict__ indeg, float* __restrict__ inv_mean,
    float* __restrict__ inv_in, float* __restrict__ inv_out) {
  int n = blockIdx.x * 256 + threadIdx.x;
  if (n >= NN) return;
  unsigned di = 0, dz = 0;
  #pragma unroll 8
  for (int sl = 0; sl < NSL; ++sl) {
    di += pd[(long)sl * NN + n];
    dz += ps[(long)sl * NN + n];
  }
  indeg[n] = (int)di;
  float fdi = fmaxf((float)di, 1.f), fdz = fmaxf((float)dz, 1.f);
  inv_mean[n] = 1.f / fdi;
  inv_in[n]  = rsqrtf(fdi);
  inv_out[n] = rsqrtf(fdz);
}

__global__ __launch_bounds__(256) void scan_block_kernel(const int* __restrict__ counts,
                                                         int* excl, int* bsum, int n) {
  __shared__ int sh[256];
  int i = blockIdx.x * 256 + threadIdx.x;
  int v = (i < n) ? counts[i] : 0;
  sh[threadIdx.x] = v;
  __syncthreads();
  #pragma unroll
  for (int off = 1; off < 256; off <<= 1) {
    int tv = (threadIdx.x >= off) ? sh[threadIdx.x - off] : 0;
    __syncthreads();
    sh[threadIdx.x] += tv;
    __syncthreads();
  }
  if (i < n) excl[i] = sh[threadIdx.x] - v;
  if (threadIdx.x == 255 && bsum) bsum[blockIdx.x] = sh[255];
}

// builds per-(slice,node) cursors AND packed nodeinfo {e0, end, inv_mean, inv_in}
__global__ void cursor_init_kernel(const int* __restrict__ row_ptr, const int* __restrict__ bsum,
                                   const unsigned* __restrict__ pd,
                                   unsigned* __restrict__ cur0,
                                   const float* __restrict__ inv_mean,
                                   const float* __restrict__ inv_in,
                                   int4* __restrict__ nodeinfo) {
  int n = blockIdx.x * 256 + threadIdx.x;
  if (n >= NN) return;
  unsigned start = (unsigned)(row_ptr[n] + bsum[n >> 8]);
  unsigned run = start;
  #pragma unroll 8
  for (int sl = 0; sl < NSL; ++sl) {
    cur0[(long)sl * NN + n] = run;
    run += pd[(long)sl * NN + n];
  }
  nodeinfo[n] = make_int4((int)start, (int)run,
                          __float_as_int(inv_mean[n]), __float_as_int(inv_in[n]));
}

__global__ __launch_bounds__(256) void fill_partial_kernel(
    const int4* __restrict__ dst4, const int4* __restrict__ src4,
    const unsigned* __restrict__ cur0, int* __restrict__ col) {
  __shared__ unsigned cur[CHK];
  const int chunk = blockIdx.x & 3;
  const int sl = blockIdx.x >> 2;
  const int lo = chunk * CHK;
  const unsigned* c0 = cur0 + (long)sl * NN + lo;
  for (int i = threadIdx.x; i < CHK; i += 256) cur[i] = c0[i];
  __syncthreads();
  const int base4 = sl * (ESL / 4);
  for (int i = threadIdx.x; i < ESL / 4; i += 256) {
    int4 d = dst4[base4 + i];
    int4 s = src4[base4 + i];
    int a;
    a = d.x - lo; if ((unsigned)a < (unsigned)CHK) col[atomicAdd(&cur[a], 1u)] = s.x;
    a = d.y - lo; if ((unsigned)a < (unsigned)CHK) col[atomicAdd(&cur[a], 1u)] = s.y;
    a = d.z - lo; if ((unsigned)a < (unsigned)CHK) col[atomicAdd(&cur[a], 1u)] = s.z;
    a = d.w - lo; if ((unsigned)a < (unsigned)CHK) col[atomicAdd(&cur[a], 1u)] = s.w;
  }
}

// ---------------- SpMM over feature-sliced fp16 table (2 slices x 64 feats) ----------------

__global__ __launch_bounds__(256) void spmm64s_kernel(
    const int4* __restrict__ nodeinfo, const int* __restrict__ cols,
    const __half* __restrict__ xs, int useW,
    float* __restrict__ out) {
  const int t = threadIdx.x;
  const int lane = t & 63;
  const int wv = t >> 6;
  const int b = blockIdx.x;
  const int xcd = b & 7;
  const int slice = xcd >> 2;
  const int sub = xcd & 3;
  const int node = (b >> 3) * 16 + wv * 4 + sub;   // exact cover: NN = 3125*16
  const int q8 = lane & 7;       // 16B chunk of the 128B row
  const int e8 = lane >> 3;      // edge slot within group of 8
  const __half* xb = xs + (long)slice * NN * 64 + q8 * 8;
  int4 ni = nodeinfo[node];
  const int e0 = ni.x, end = ni.y;
  const float d = __int_as_float(useW ? ni.w : ni.z);
  const int end1 = end - 1;
  float a0 = 0.f, a1 = 0.f, a2 = 0.f, a3 = 0.f, a4 = 0.f, a5 = 0.f, a6 = 0.f, a7 = 0.f;
  float c0 = 0.f, c1 = 0.f, c2 = 0.f, c3 = 0.f, c4 = 0.f, c5 = 0.f, c6 = 0.f, c7 = 0.f;
  for (int e = e0; e < end; e += 16) {
    int ee0 = e + e8;
    int ee1 = ee0 + 8;
    int ec0 = ee0 < end ? ee0 : end1;
    int ec1 = ee1 < end ? ee1 : end1;
    int s0 = cols[ec0];
    int s1 = cols[ec1];
    float m0 = ee0 < end ? 1.f : 0.f;
    float m1 = ee1 < end ? 1.f : 0.f;
    f32x4 v0 = *(const f32x4*)(xb + (unsigned)s0 * 64u);
    f32x4 v1 = *(const f32x4*)(xb + (unsigned)s1 * 64u);
    const __half2* h0 = (const __half2*)&v0;
    const __half2* h1 = (const __half2*)&v1;
    float2 f0 = __half22float2(h0[0]), f1 = __half22float2(h0[1]);
    float2 f2 = __half22float2(h0[2]), f3 = __half22float2(h0[3]);
    float2 g0 = __half22float2(h1[0]), g1 = __half22float2(h1[1]);
    float2 g2 = __half22float2(h1[2]), g3 = __half22float2(h1[3]);
    a0 = fmaf(f0.x, m0, a0); a1 = fmaf(f0.y, m0, a1);
    a2 = fmaf(f1.x, m0, a2); a3 = fmaf(f1.y, m0, a3);
    a4 = fmaf(f2.x, m0, a4); a5 = fmaf(f2.y, m0, a5);
    a6 = fmaf(f3.x, m0, a6); a7 = fmaf(f3.y, m0, a7);
    c0 = fmaf(g0.x, m1, c0); c1 = fmaf(g0.y, m1, c1);
    c2 = fmaf(g1.x, m1, c2); c3 = fmaf(g1.y, m1, c3);
    c4 = fmaf(g2.x, m1, c4); c5 = fmaf(g2.y, m1, c5);
    c6 = fmaf(g3.x, m1, c6); c7 = fmaf(g3.y, m1, c7);
  }
  a0 += c0; a1 += c1; a2 += c2; a3 += c3;
  a4 += c4; a5 += c5; a6 += c6; a7 += c7;
  #pragma unroll
  for (int m = 8; m < 64; m <<= 1) {
    a0 += __shfl_xor(a0, m, 64); a1 += __shfl_xor(a1, m, 64);
    a2 += __shfl_xor(a2, m, 64); a3 += __shfl_xor(a3, m, 64);
    a4 += __shfl_xor(a4, m, 64); a5 += __shfl_xor(a5, m, 64);
    a6 += __shfl_xor(a6, m, 64); a7 += __shfl_xor(a7, m, 64);
  }
  if (lane < 8) {
    float* op = out + (long)node * HF + slice * 64 + q8 * 8;
    *(f32x4*)op       = (f32x4){a0 * d, a1 * d, a2 * d, a3 * d};
    *(f32x4*)(op + 4) = (f32x4){a4 * d, a5 * d, a6 * d, a7 * d};
  }
}

// ---------------- attention gate + gated residual ----------------

__global__ __launch_bounds__(128) void attn_hatt_kernel(
    const float* __restrict__ a, const float* __restrict__ w2, const float* __restrict__ b2,
    const float* __restrict__ h0, const float* __restrict__ agg,
    const float* __restrict__ inv_out,
    __half* __restrict__ hatt16) {
  int r = blockIdx.x, f = threadIdx.x;
  long idx = (long)r * HF + f;
  float v = a[idx] * w2[f];
  #pragma unroll
  for (int off = 32; off >= 1; off >>= 1) v += __shfl_down(v, off, 64);
  __shared__ float red[2];
  if ((f & 63) == 0) red[f >> 6] = v;
  __syncthreads();
  float dot = red[0] + red[1] + b2[0];
  float s = 1.f / (1.f + __expf(-dot));
  float h = h0[idx] + agg[idx] * s;
  hatt16[((long)(f >> 6) * NN + r) * 64 + (f & 63)] = __float2half(h * inv_out[r]);
}

// ---------------- weight prepack: fp32 W[K][N] -> bf16 hi/lo MFMA fragments ----------------

__global__ void prepack_kernel(const float* __restrict__ W, int N, int ldw, int NTpad,
                               ushort* __restrict__ hi, ushort* __restrict__ lo, int total) {
  int idx = blockIdx.x * 256 + threadIdx.x;
  if (idx >= total) return;
  int j    = idx & 7;
  int lane = (idx >> 3) & 63;
  int rest = idx >> 9;
  int nt = rest % NTpad;
  int kc = rest / NTpad;
  int k = kc * 32 + (lane >> 4) * 8 + j;
  int n = nt * 16 + (lane & 15);
  float w = (n < N) ? W[(long)k * ldw + n] : 0.f;
  ushort h = f2bf(w);
  hi[idx] = h;
  lo[idx] = f2bf(w - bf2f(h));
}

// ---------------- split-bf16 MFMA GEMM: out = epi( [A1|A2] @ W + bias ) ----------------
// Block = 16 rows x 128 cols, 4 waves; wave = 16 rows x NT*16 cols (colbase=wid*NT*16).
// 3125 blocks -> 12.2 blocks/CU x 4 waves = 48 waves/CU -> occupancy saturated.
// NTP = prepack column pad of B. fp32 A, split in-loop (A rows block-shared -> L1 hits).

template<int KC, int NT, int NTP, int EPI, int H16>
__global__ __launch_bounds__(256) void mgemm_kernel(
    const float* __restrict__ A1, int lda1,
    const float* __restrict__ A2, int lda2,
    const ushort* __restrict__ Bhi, const ushort* __restrict__ Blo,
    const float* __restrict__ bias,
    const float* __restrict__ g, const float* __restrict__ be,
    const float* __restrict__ mu, const float* __restrict__ va,
    const float* __restrict__ res,
    float* __restrict__ out, int ldc, int Ncols,
    __half* __restrict__ out16, const float* __restrict__ rowscale) {
  const int t = threadIdx.x;
  const int lane = t & 63;
  const int wid = t >> 6;
  const int rowbase = blockIdx.x * 16;
  const int arow = rowbase + (lane & 15);
  const int kgrp = (lane >> 4) * 8;
  const int colbase = wid * NT * 16;
  if (colbase >= Ncols) return;   // wave-uniform (unused col waves exit)

  f32x4 acc[NT];
  #pragma unroll
  for (int n = 0; n < NT; ++n) acc[n] = (f32x4){0.f, 0.f, 0.f, 0.f};

  for (int kc = 0; kc < KC; ++kc) {
    const bool second = (KC == 8) && (kc >= 4);
    const float* Ap = second ? A2 : A1;
    const int lda = second ? lda2 : lda1;
    const long kb = (long)(second ? (kc - 4) * 32 : kc * 32) + kgrp;

    const f32x4 z4 = {0.f, 0.f, 0.f, 0.f};
    f32x4 ava = z4, avb = z4;
    if (arow < NN) {
      const float* p = Ap + (long)arow * lda + kb;
      ava = *(const f32x4*)p;
      avb = *(const f32x4*)(p + 4);
    }

    bf16x8 ah, al;
    #pragma unroll
    for (int j = 0; j < 8; ++j) {
      float v0 = (j < 4) ? ava[j] : avb[j - 4];
      ushort h0 = f2bf(v0);
      ah[j] = (short)h0;
      al[j] = (short)f2bf(v0 - bf2f(h0));
    }

    const ushort* bh = Bhi + ((long)kc * NTP * 64 + lane) * 8 + (long)wid * NT * 512;
    const ushort* bl = Blo + ((long)kc * NTP * 64 + lane) * 8 + (long)wid * NT * 512;
    #pragma unroll
    for (int nt = 0; nt < NT; ++nt) {
      bf16x8 bhv = *(const bf16x8*)(bh + (long)nt * 512);
      bf16x8 blv = *(const bf16x8*)(bl + (long)nt * 512);
      acc[nt] = __builtin_amdgcn_mfma_f32_16x16x32_bf16(ah, bhv, acc[nt], 0, 0, 0);
      acc[nt] = __builtin_amdgcn_mfma_f32_16x16x32_bf16(al, bhv, acc[nt], 0, 0, 0);
      acc[nt] = __builtin_amdgcn_mfma_f32_16x16x32_bf16(ah, blv, acc[nt], 0, 0, 0);
    }
  }

  const int colg = lane & 15;
  const int rsub = (lane >> 4) * 4;
  #pragma unroll
  for (int nt = 0; nt < NT; ++nt) {
    int c = colbase + nt * 16 + colg;
    if (c >= Ncols) continue;
    float bb = bias ? bias[c] : 0.f;
    float scale = 1.f, shift = 0.f;
    if (EPI == EPI_BN || EPI == EPI_BN_RES) {
      scale = g[c] * rsqrtf(va[c] + EPSV);
      shift = be[c] - mu[c] * scale;
    }
    #pragma unroll
    for (int i = 0; i < 4; ++i) {
      int r = rowbase + rsub + i;
      if (r >= NN) continue;
      float v = acc[nt][i] + bb;
      if (EPI == EPI_RELU) {
        v = fmaxf(v, 0.f);
      } else if (EPI == EPI_BN || EPI == EPI_BN_RES) {
        v = fmaxf(v * scale + shift, 0.f);
        if (EPI == EPI_BN_RES) v += res[(long)r * HF + c];
      }
      out[(long)r * ldc + c] = v;
      if (H16 != H16_NONE) {
        float sc = (H16 == H16_SCALED) ? rowscale[r] : 1.f;
        out16[((long)(c >> 6) * NN + r) * 64 + (c & 63)] = __float2half(v * sc);
      }
    }
  }
}

// ---------------- launch ----------------

extern "C" void kernel_launch(void* const* d_in, const int* in_sizes, int n_in,
                              void* d_out, int out_size, void* d_ws, size_t ws_size,
                              hipStream_t stream) {
  const float* features = (const float*)d_in[0];
  const int*   src      = (const int*)d_in[1];
  const int*   dst      = (const int*)d_in[2];
  const float* w_in     = (const float*)d_in[3];
  const float* b_in     = (const float*)d_in[4];
  const float* gc_w     = (const float*)d_in[5];
  const float* gc_b     = (const float*)d_in[6];
  const float* bn_gamma = (const float*)d_in[7];
  const float* bn_beta  = (const float*)d_in[8];
  const float* bn_mean  = (const float*)d_in[9];
  const float* bn_var   = (const float*)d_in[10];
  const float* attn_w1  = (const float*)d_in[11];
  const float* attn_b1  = (const float*)d_in[12];
  const float* attn_w2  = (const float*)d_in[13];
  const float* attn_b2  = (const float*)d_in[14];
  const float* agg_w    = (const float*)d_in[15];
  const float* agg_b    = (const float*)d_in[16];
  const float* out_w    = (const float*)d_in[17];
  const float* out_b    = (const float*)d_in[18];
  float* out = (float*)d_out;

  float* fbase   = (float*)d_ws;
  float* W0 = fbase;                 // h0 -> spmm scratch
  float* W1 = fbase + NH;            // neigh -> a -> rst1
  float* W2 = fbase + 2 * NH;        // agg -> rst0 -> rst2
  float* inv_mean = fbase + 3 * NH;
  float* inv_in   = inv_mean + NN;
  float* inv_out  = inv_in + NN;
  int* indeg   = (int*)(inv_out + NN);
  int* row_ptr = indeg + NN;         // NN+16
  int* bsum    = row_ptr + NN + 16;  // 256
  int* col     = bsum + 256;         // EE
  int4* nodeinfo = (int4*)(col + EE);

  // preprocessing scratch aliased into W1/W2 (dead before their first writes)
  unsigned* pd   = (unsigned*)W1;
  unsigned* ps   = pd + (long)NSL * NN;
  unsigned* cur0 = ps + (long)NSL * NN;

  // packed bf16 hi/lo weights
  ushort* pk = (ushort*)(nodeinfo + NN);
  const int SZ256 = 8 * 8 * 512;     // K=256, NTP=8
  const int SZ128 = 4 * 8 * 512;     // K=128, NTP=8
  const int SZOUT = 4 * 4 * 512;     // K=128, NTP=4
  ushort* win_hi = pk;  pk += SZ256;  ushort* win_lo = pk;  pk += SZ256;
  ushort* agg_hi = pk;  pk += SZ256;  ushort* agg_lo = pk;  pk += SZ256;
  ushort* at1_hi = pk;  pk += SZ256;  ushort* at1_lo = pk;  pk += SZ256;
  ushort* gch[3], *gcl[3];
  for (int i = 0; i < 3; ++i) { gch[i] = pk; pk += SZ128; gcl[i] = pk; pk += SZ128; }
  ushort* ow_hi = pk;  pk += SZOUT;   ushort* ow_lo = pk;  pk += SZOUT;
  __half* X16 = (__half*)pk;          // NH halfs, sliced [2][NN][64]

  dim3 b256(256), b128(128);
  const int gN = (NN + 255) / 256;
  const int gblocks = (NN + 15) / 16;     // 3125
  const int gspmm = (NN / 16) * 8;        // 25000
  const int gpre = NSL * 4;

  // graph preprocessing (no global atomics)
  count_partial_kernel<<<gpre, b256, 0, stream>>>((const int4*)dst, pd);
  count_partial_kernel<<<gpre, b256, 0, stream>>>((const int4*)src, ps);
  reduce_deg_kernel<<<gN, b256, 0, stream>>>(pd, ps, indeg, inv_mean, inv_in, inv_out);
  scan_block_kernel<<<gN, b256, 0, stream>>>(indeg, row_ptr, bsum, NN);
  scan_block_kernel<<<1, b256, 0, stream>>>(bsum, bsum, nullptr, gN);
  cursor_init_kernel<<<gN, b256, 0, stream>>>(row_ptr, bsum, pd, cur0, inv_mean, inv_in, nodeinfo);
  fill_partial_kernel<<<gpre, b256, 0, stream>>>((const int4*)dst, (const int4*)src, cur0, col);

  // weight prepack
  prepack_kernel<<<(SZ256 + 255) / 256, b256, 0, stream>>>(w_in,    HF, HF, 8, win_hi, win_lo, SZ256);
  prepack_kernel<<<(SZ256 + 255) / 256, b256, 0, stream>>>(agg_w,   HF, HF, 8, agg_hi, agg_lo, SZ256);
  prepack_kernel<<<(SZ256 + 255) / 256, b256, 0, stream>>>(attn_w1, HF, HF, 8, at1_hi, at1_lo, SZ256);
  for (int i = 0; i < 3; ++i)
    prepack_kernel<<<(SZ128 + 255) / 256, b256, 0, stream>>>(gc_w + (long)i * HF * HF, HF, HF, 8, gch[i], gcl[i], SZ128);
  prepack_kernel<<<(SZOUT + 255) / 256, b256, 0, stream>>>(out_w, CC, CC, 4, ow_hi, ow_lo, SZOUT);

  // h0 = relu(features @ w_in + b_in)            -> W0 (+fp16 raw sliced -> X16)
  mgemm_kernel<8, 2, 8, EPI_RELU, H16_RAW><<<gblocks, b256, 0, stream>>>(
      features, INF_, features + 128, INF_, win_hi, win_lo, b_in,
      nullptr, nullptr, nullptr, nullptr, nullptr, W0, HF, HF, X16, nullptr);
  // neigh = mean-agg(h0)                          -> W1
  spmm64s_kernel<<<gspmm, b256, 0, stream>>>(nodeinfo, col, X16, 0, W1);
  // agg = relu([h0|neigh] @ agg_w + agg_b)        -> W2
  mgemm_kernel<8, 2, 8, EPI_RELU, H16_NONE><<<gblocks, b256, 0, stream>>>(
      W0, HF, W1, HF, agg_hi, agg_lo, agg_b,
      nullptr, nullptr, nullptr, nullptr, nullptr, W2, HF, HF, nullptr, nullptr);
  // a = relu([h0|agg] @ attn_w1 + attn_b1)        -> W1
  mgemm_kernel<8, 2, 8, EPI_RELU, H16_NONE><<<gblocks, b256, 0, stream>>>(
      W0, HF, W2, HF, at1_hi, at1_lo, attn_b1,
      nullptr, nullptr, nullptr, nullptr, nullptr, W1, HF, HF, nullptr, nullptr);
  // h_att = h0 + agg * sigmoid(a@w2+b2)           -> X16 (scaled by inv_out)
  attn_hatt_kernel<<<NN, b128, 0, stream>>>(W1, attn_w2, attn_b2, W0, W2, inv_out, X16);

  // layer 0: spmm(X16)->W0 ; rst0 = relu(BN(W0@gc0+b0))   -> W2 + X16
  spmm64s_kernel<<<gspmm, b256, 0, stream>>>(nodeinfo, col, X16, 1, W0);
  mgemm_kernel<4, 2, 8, EPI_BN, H16_SCALED><<<gblocks, b256, 0, stream>>>(
      W0, HF, nullptr, 0, gch[0], gcl[0], gc_b,
      bn_gamma, bn_beta, bn_mean, bn_var, nullptr, W2, HF, HF, X16, inv_out);
  // layer 1: spmm(X16)->W0 ; rst1 = relu(BN(W0@gc1+b1)) + rst0 -> W1 + X16
  spmm64s_kernel<<<gspmm, b256, 0, stream>>>(nodeinfo, col, X16, 1, W0);
  mgemm_kernel<4, 2, 8, EPI_BN_RES, H16_SCALED><<<gblocks, b256, 0, stream>>>(
      W0, HF, nullptr, 0, gch[1], gcl[1], gc_b + HF,
      bn_gamma + HF, bn_beta + HF, bn_mean + HF, bn_var + HF, W2, W1, HF, HF, X16, inv_out);
  // layer 2: spmm(X16)->W0 ; rst2 = relu(BN(W0@gc2+b2)) + rst1 -> W2
  spmm64s_kernel<<<gspmm, b256, 0, stream>>>(nodeinfo, col, X16, 1, W0);
  mgemm_kernel<4, 2, 8, EPI_BN_RES, H16_NONE><<<gblocks, b256, 0, stream>>>(
      W0, HF, nullptr, 0, gch[2], gcl[2], gc_b + 2 * HF,
      bn_gamma + 2 * HF, bn_beta + 2 * HF, bn_mean + 2 * HF, bn_var + 2 * HF, W1, W2, HF, HF,
      nullptr, nullptr);

  // out = rst2 @ out_w + out_b                    -> d_out
  mgemm_kernel<4, 1, 4, EPI_NONE, H16_NONE><<<gblocks, b256, 0, stream>>>(
      W2, HF, nullptr, 0, ow_hi, ow_lo, out_b,
      nullptr, nullptr, nullptr, nullptr, nullptr, out, CC, CC, nullptr, nullptr);
}

// Round 12
// 457.046 us; speedup vs baseline: 1.0291x; 1.0291x over previous
//
#include <hip/hip_runtime.h>
#include <hip/hip_fp16.h>
#include <math.h>

constexpr int NN  = 50000;   // nodes
constexpr int EE  = 800000;  // edges
constexpr int INF_ = 256;    // input feat
constexpr int HF  = 128;     // hidden
constexpr int CC  = 50;      // classes
constexpr long NH = (long)NN * HF;
constexpr int NSL = 32;          // edge slices (preprocessing)
constexpr int ESL = EE / NSL;    // 25000 edges per slice
constexpr int CHK = 12500;       // nodes per chunk (4 chunks), 50KB LDS
#define EPSV 1e-5f

enum { EPI_RELU = 0, EPI_NONE = 1, EPI_BN = 2, EPI_BN_RES = 3 };
enum { H16_NONE = 0, H16_RAW = 1, H16_SCALED = 2 };

typedef __attribute__((ext_vector_type(4))) float f32x4;
typedef __attribute__((ext_vector_type(8))) short bf16x8;

__device__ __forceinline__ ushort f2bf(float f) {
  union { float f; unsigned u; } v; v.f = f;
  unsigned r = (v.u + 0x7fffu + ((v.u >> 16) & 1u)) >> 16;  // RNE
  return (ushort)r;
}
__device__ __forceinline__ float bf2f(ushort u) {
  union { unsigned u; float f; } v; v.u = ((unsigned)u) << 16;
  return v.f;
}
// packed activation: hi bf16 in low16, lo bf16 in high16 (4B, fp32-like stores)
__device__ __forceinline__ unsigned packbf(float v) {
  ushort h = f2bf(v);
  return (unsigned)h | ((unsigned)f2bf(v - bf2f(h)) << 16);
}
__device__ __forceinline__ float unpackbf(unsigned p) {
  return bf2f((ushort)p) + bf2f((ushort)(p >> 16));
}

// ---------------- graph preprocessing (atomic-free: LDS histograms) ----------------

__global__ __launch_bounds__(256) void count_partial_kernel(
    const int4* __restrict__ keys4, unsigned* __restrict__ partials) {
  __shared__ unsigned cnt[CHK];
  const int chunk = blockIdx.x & 3;
  const int sl = blockIdx.x >> 2;
  for (int i = threadIdx.x; i < CHK; i += 256) cnt[i] = 0;
  __syncthreads();
  const int base4 = sl * (ESL / 4);
  const int lo = chunk * CHK;
  for (int i = threadIdx.x; i < ESL / 4; i += 256) {
    int4 k = keys4[base4 + i];
    int a;
    a = k.x - lo; if ((unsigned)a < (unsigned)CHK) atomicAdd(&cnt[a], 1u);
    a = k.y - lo; if ((unsigned)a < (unsigned)CHK) atomicAdd(&cnt[a], 1u);
    a = k.z - lo; if ((unsigned)a < (unsigned)CHK) atomicAdd(&cnt[a], 1u);
    a = k.w - lo; if ((unsigned)a < (unsigned)CHK) atomicAdd(&cnt[a], 1u);
  }
  __syncthreads();
  unsigned* p = partials + (long)sl * NN + lo;
  for (int i = threadIdx.x; i < CHK; i += 256) p[i] = cnt[i];
}

__global__ __launch_bounds__(256) void reduce_deg_kernel(
    const unsigned* __restrict__ pd, const unsigned* __restrict__ ps,
    int* __restrict__ indeg, float* __restrict__ inv_mean,
    float* __restrict__ inv_in, float* __restrict__ inv_out) {
  int n = blockIdx.x * 256 + threadIdx.x;
  if (n >= NN) return;
  unsigned di = 0, dz = 0;
  #pragma unroll 8
  for (int sl = 0; sl < NSL; ++sl) {
    di += pd[(long)sl * NN + n];
    dz += ps[(long)sl * NN + n];
  }
  indeg[n] = (int)di;
  float fdi = fmaxf((float)di, 1.f), fdz = fmaxf((float)dz, 1.f);
  inv_mean[n] = 1.f / fdi;
  inv_in[n]  = rsqrtf(fdi);
  inv_out[n] = rsqrtf(fdz);
}

__global__ __launch_bounds__(256) void scan_block_kernel(const int* __restrict__ counts,
                                                         int* excl, int* bsum, int n) {
  __shared__ int sh[256];
  int i = blockIdx.x * 256 + threadIdx.x;
  int v = (i < n) ? counts[i] : 0;
  sh[threadIdx.x] = v;
  __syncthreads();
  #pragma unroll
  for (int off = 1; off < 256; off <<= 1) {
    int tv = (threadIdx.x >= off) ? sh[threadIdx.x - off] : 0;
    __syncthreads();
    sh[threadIdx.x] += tv;
    __syncthreads();
  }
  if (i < n) excl[i] = sh[threadIdx.x] - v;
  if (threadIdx.x == 255 && bsum) bsum[blockIdx.x] = sh[255];
}

// builds per-(slice,node) cursors AND packed nodeinfo {e0, end, inv_mean, inv_in}
__global__ void cursor_init_kernel(const int* __restrict__ row_ptr, const int* __restrict__ bsum,
                                   const unsigned* __restrict__ pd,
                                   unsigned* __restrict__ cur0,
                                   const float* __restrict__ inv_mean,
                                   const float* __restrict__ inv_in,
                                   int4* __restrict__ nodeinfo) {
  int n = blockIdx.x * 256 + threadIdx.x;
  if (n >= NN) return;
  unsigned start = (unsigned)(row_ptr[n] + bsum[n >> 8]);
  unsigned run = start;
  #pragma unroll 8
  for (int sl = 0; sl < NSL; ++sl) {
    cur0[(long)sl * NN + n] = run;
    run += pd[(long)sl * NN + n];
  }
  nodeinfo[n] = make_int4((int)start, (int)run,
                          __float_as_int(inv_mean[n]), __float_as_int(inv_in[n]));
}

__global__ __launch_bounds__(256) void fill_partial_kernel(
    const int4* __restrict__ dst4, const int4* __restrict__ src4,
    const unsigned* __restrict__ cur0, int* __restrict__ col) {
  __shared__ unsigned cur[CHK];
  const int chunk = blockIdx.x & 3;
  const int sl = blockIdx.x >> 2;
  const int lo = chunk * CHK;
  const unsigned* c0 = cur0 + (long)sl * NN + lo;
  for (int i = threadIdx.x; i < CHK; i += 256) cur[i] = c0[i];
  __syncthreads();
  const int base4 = sl * (ESL / 4);
  for (int i = threadIdx.x; i < ESL / 4; i += 256) {
    int4 d = dst4[base4 + i];
    int4 s = src4[base4 + i];
    int a;
    a = d.x - lo; if ((unsigned)a < (unsigned)CHK) col[atomicAdd(&cur[a], 1u)] = s.x;
    a = d.y - lo; if ((unsigned)a < (unsigned)CHK) col[atomicAdd(&cur[a], 1u)] = s.y;
    a = d.z - lo; if ((unsigned)a < (unsigned)CHK) col[atomicAdd(&cur[a], 1u)] = s.z;
    a = d.w - lo; if ((unsigned)a < (unsigned)CHK) col[atomicAdd(&cur[a], 1u)] = s.w;
  }
}

// ---------------- SpMM over feature-sliced fp16 table (2 slices x 64 feats) ----------------
// fp16 accumulate in the main loop (8 v_pk_add_f16 per 2 edges; chain = deg/16 adds),
// masks peeled to a tail; f32 shuffle-tree reduce; packed bf16x2 output.

__global__ __launch_bounds__(256) void spmm64s_kernel(
    const int4* __restrict__ nodeinfo, const int* __restrict__ cols,
    const __half* __restrict__ xs, int useW,
    unsigned* __restrict__ outp) {
  const int t = threadIdx.x;
  const int lane = t & 63;
  const int wv = t >> 6;
  const int b = blockIdx.x;
  const int xcd = b & 7;
  const int slice = xcd >> 2;
  const int sub = xcd & 3;
  const int node = (b >> 3) * 16 + wv * 4 + sub;   // exact cover: NN = 3125*16
  const int q8 = lane & 7;       // 16B chunk of the 128B row
  const int e8 = lane >> 3;      // edge slot within group of 8
  const __half* xb = xs + (long)slice * NN * 64 + q8 * 8;
  int4 ni = nodeinfo[node];
  const int e0 = ni.x, end = ni.y;
  const float d = __int_as_float(useW ? ni.w : ni.z);
  const __half2 z2 = __float2half2_rn(0.f);
  __half2 A0 = z2, A1 = z2, A2 = z2, A3 = z2;
  __half2 C0 = z2, C1 = z2, C2 = z2, C3 = z2;
  const int nfull = (end - e0) & ~15;
  int e = e0;
  for (; e < e0 + nfull; e += 16) {
    int s0 = cols[e + e8];
    int s1 = cols[e + 8 + e8];
    f32x4 v0 = *(const f32x4*)(xb + (unsigned)s0 * 64u);
    f32x4 v1 = *(const f32x4*)(xb + (unsigned)s1 * 64u);
    const __half2* h0 = (const __half2*)&v0;
    const __half2* h1 = (const __half2*)&v1;
    A0 = __hadd2(A0, h0[0]); A1 = __hadd2(A1, h0[1]);
    A2 = __hadd2(A2, h0[2]); A3 = __hadd2(A3, h0[3]);
    C0 = __hadd2(C0, h1[0]); C1 = __hadd2(C1, h1[1]);
    C2 = __hadd2(C2, h1[2]); C3 = __hadd2(C3, h1[3]);
  }
  if (e < end) {               // tail: <16 edges, per-lane predicated
    int ee0 = e + e8;
    if (ee0 < end) {
      int s0 = cols[ee0];
      f32x4 v0 = *(const f32x4*)(xb + (unsigned)s0 * 64u);
      const __half2* h0 = (const __half2*)&v0;
      A0 = __hadd2(A0, h0[0]); A1 = __hadd2(A1, h0[1]);
      A2 = __hadd2(A2, h0[2]); A3 = __hadd2(A3, h0[3]);
    }
    int ee1 = e + 8 + e8;
    if (ee1 < end) {
      int s1 = cols[ee1];
      f32x4 v1 = *(const f32x4*)(xb + (unsigned)s1 * 64u);
      const __half2* h1 = (const __half2*)&v1;
      C0 = __hadd2(C0, h1[0]); C1 = __hadd2(C1, h1[1]);
      C2 = __hadd2(C2, h1[2]); C3 = __hadd2(C3, h1[3]);
    }
  }
  float2 f0 = __half22float2(A0), f1 = __half22float2(A1);
  float2 f2 = __half22float2(A2), f3 = __half22float2(A3);
  float2 g0 = __half22float2(C0), g1 = __half22float2(C1);
  float2 g2 = __half22float2(C2), g3 = __half22float2(C3);
  float a0 = f0.x + g0.x, a1 = f0.y + g0.y;
  float a2 = f1.x + g1.x, a3 = f1.y + g1.y;
  float a4 = f2.x + g2.x, a5 = f2.y + g2.y;
  float a6 = f3.x + g3.x, a7 = f3.y + g3.y;
  #pragma unroll
  for (int m = 8; m < 64; m <<= 1) {
    a0 += __shfl_xor(a0, m, 64); a1 += __shfl_xor(a1, m, 64);
    a2 += __shfl_xor(a2, m, 64); a3 += __shfl_xor(a3, m, 64);
    a4 += __shfl_xor(a4, m, 64); a5 += __shfl_xor(a5, m, 64);
    a6 += __shfl_xor(a6, m, 64); a7 += __shfl_xor(a7, m, 64);
  }
  if (lane < 8) {
    unsigned* op = outp + (long)node * HF + slice * 64 + q8 * 8;
    uint4 w0 = make_uint4(packbf(a0 * d), packbf(a1 * d), packbf(a2 * d), packbf(a3 * d));
    uint4 w1 = make_uint4(packbf(a4 * d), packbf(a5 * d), packbf(a6 * d), packbf(a7 * d));
    *(uint4*)op       = w0;
    *(uint4*)(op + 4) = w1;
  }
}

// ---------------- attention gate + gated residual (packed inputs) ----------------

__global__ __launch_bounds__(128) void attn_hatt_kernel(
    const float* __restrict__ a, const float* __restrict__ w2, const float* __restrict__ b2,
    const unsigned* __restrict__ h0p, const unsigned* __restrict__ aggp,
    const float* __restrict__ inv_out,
    __half* __restrict__ hatt16) {
  int r = blockIdx.x, f = threadIdx.x;
  long idx = (long)r * HF + f;
  float v = a[idx] * w2[f];
  #pragma unroll
  for (int off = 32; off >= 1; off >>= 1) v += __shfl_down(v, off, 64);
  __shared__ float red[2];
  if ((f & 63) == 0) red[f >> 6] = v;
  __syncthreads();
  float dot = red[0] + red[1] + b2[0];
  float s = 1.f / (1.f + __expf(-dot));
  float h = unpackbf(h0p[idx]) + unpackbf(aggp[idx]) * s;
  hatt16[((long)(f >> 6) * NN + r) * 64 + (f & 63)] = __float2half(h * inv_out[r]);
}

// ---------------- weight prepack: fp32 W[K][N] -> bf16 hi/lo MFMA fragments ----------------

__global__ void prepack_kernel(const float* __restrict__ W, int N, int ldw, int NTpad,
                               ushort* __restrict__ hi, ushort* __restrict__ lo, int total) {
  int idx = blockIdx.x * 256 + threadIdx.x;
  if (idx >= total) return;
  int j    = idx & 7;
  int lane = (idx >> 3) & 63;
  int rest = idx >> 9;
  int nt = rest % NTpad;
  int kc = rest / NTpad;
  int k = kc * 32 + (lane >> 4) * 8 + j;
  int n = nt * 16 + (lane & 15);
  float w = (n < N) ? W[(long)k * ldw + n] : 0.f;
  ushort h = f2bf(w);
  hi[idx] = h;
  lo[idx] = f2bf(w - bf2f(h));
}

// ---------------- split-bf16 MFMA GEMM: out = epi( [A1|A2] @ W + bias ) ----------------
// Block = 64 rows x 128 cols, 4 waves; wave = 16 rows x NT*16 cols (782 blocks).
// ASRC=0: A fp32, split in-loop (features only). ASRC=1: A packed bf16x2 ->
// v_perm deinterleave (8 perms per row-fragment per kc, no split VALU).
// OUTM=0: fp32 out. OUTM=1: packed bf16x2 out.

template<int KC, int NT, int NTP, int EPI, int H16, int ASRC, int OUTM>
__global__ __launch_bounds__(256) void mgemm_kernel(
    const void* __restrict__ A1, int lda1,
    const void* __restrict__ A2, int lda2,
    const ushort* __restrict__ Bhi, const ushort* __restrict__ Blo,
    const float* __restrict__ bias,
    const float* __restrict__ g, const float* __restrict__ be,
    const float* __restrict__ mu, const float* __restrict__ va,
    const unsigned* __restrict__ res,
    float* __restrict__ outf, unsigned* __restrict__ outp, int ldc, int Ncols,
    __half* __restrict__ out16, const float* __restrict__ rowscale) {
  const int t = threadIdx.x;
  const int lane = t & 63;
  const int wid = t >> 6;
  const int rowbase = blockIdx.x * 64 + wid * 16;
  const int arow = rowbase + (lane & 15);
  const int kgrp = (lane >> 4) * 8;

  f32x4 acc[NT];
  #pragma unroll
  for (int n = 0; n < NT; ++n) acc[n] = (f32x4){0.f, 0.f, 0.f, 0.f};

  for (int kc = 0; kc < KC; ++kc) {
    const bool second = (KC == 8) && (kc >= 4);
    const int lda = second ? lda2 : lda1;
    const long kb = (long)(second ? (kc - 4) * 32 : kc * 32) + kgrp;

    bf16x8 ah, al;
    if (ASRC == 0) {
      const float* Ap = (const float*)(second ? A2 : A1);
      const f32x4 z4 = {0.f, 0.f, 0.f, 0.f};
      f32x4 ava = z4, avb = z4;
      if (arow < NN) {
        const float* p = Ap + (long)arow * lda + kb;
        ava = *(const f32x4*)p;
        avb = *(const f32x4*)(p + 4);
      }
      #pragma unroll
      for (int j = 0; j < 8; ++j) {
        float v0 = (j < 4) ? ava[j] : avb[j - 4];
        ushort h0 = f2bf(v0);
        ah[j] = (short)h0;
        al[j] = (short)f2bf(v0 - bf2f(h0));
      }
    } else {
      const unsigned* Ap = (const unsigned*)(second ? A2 : A1);
      uint4 d0 = make_uint4(0, 0, 0, 0), d1 = make_uint4(0, 0, 0, 0);
      if (arow < NN) {
        const unsigned* p = Ap + (long)arow * lda + kb;
        d0 = *(const uint4*)p;
        d1 = *(const uint4*)(p + 4);
      }
      union { unsigned u[4]; bf16x8 v; } H, L;
      H.u[0] = __builtin_amdgcn_perm(d0.y, d0.x, 0x05040100u);
      H.u[1] = __builtin_amdgcn_perm(d0.w, d0.z, 0x05040100u);
      H.u[2] = __builtin_amdgcn_perm(d1.y, d1.x, 0x05040100u);
      H.u[3] = __builtin_amdgcn_perm(d1.w, d1.z, 0x05040100u);
      L.u[0] = __builtin_amdgcn_perm(d0.y, d0.x, 0x07060302u);
      L.u[1] = __builtin_amdgcn_perm(d0.w, d0.z, 0x07060302u);
      L.u[2] = __builtin_amdgcn_perm(d1.y, d1.x, 0x07060302u);
      L.u[3] = __builtin_amdgcn_perm(d1.w, d1.z, 0x07060302u);
      ah = H.v;
      al = L.v;
    }

    const ushort* bh = Bhi + ((long)kc * NTP * 64 + lane) * 8;
    const ushort* bl = Blo + ((long)kc * NTP * 64 + lane) * 8;
    #pragma unroll
    for (int nt = 0; nt < NT; ++nt) {
      bf16x8 bhv = *(const bf16x8*)(bh + (long)nt * 512);
      bf16x8 blv = *(const bf16x8*)(bl + (long)nt * 512);
      acc[nt] = __builtin_amdgcn_mfma_f32_16x16x32_bf16(ah, bhv, acc[nt], 0, 0, 0);
      acc[nt] = __builtin_amdgcn_mfma_f32_16x16x32_bf16(al, bhv, acc[nt], 0, 0, 0);
      acc[nt] = __builtin_amdgcn_mfma_f32_16x16x32_bf16(ah, blv, acc[nt], 0, 0, 0);
    }
  }

  const int colg = lane & 15;
  const int rsub = (lane >> 4) * 4;
  #pragma unroll
  for (int nt = 0; nt < NT; ++nt) {
    int c = nt * 16 + colg;
    if (c >= Ncols) continue;
    float bb = bias ? bias[c] : 0.f;
    float scale = 1.f, shift = 0.f;
    if (EPI == EPI_BN || EPI == EPI_BN_RES) {
      scale = g[c] * rsqrtf(va[c] + EPSV);
      shift = be[c] - mu[c] * scale;
    }
    #pragma unroll
    for (int i = 0; i < 4; ++i) {
      int r = rowbase + rsub + i;
      if (r >= NN) continue;
      long ridx = (long)r * HF + c;
      float v = acc[nt][i] + bb;
      if (EPI == EPI_RELU) {
        v = fmaxf(v, 0.f);
      } else if (EPI == EPI_BN || EPI == EPI_BN_RES) {
        v = fmaxf(v * scale + shift, 0.f);
        if (EPI == EPI_BN_RES) v += unpackbf(res[ridx]);
      }
      if (OUTM == 0) {
        outf[(long)r * ldc + c] = v;
      } else {
        outp[ridx] = packbf(v);
      }
      if (H16 != H16_NONE) {
        float sc = (H16 == H16_SCALED) ? rowscale[r] : 1.f;
        out16[((long)(c >> 6) * NN + r) * 64 + (c & 63)] = __float2half(v * sc);
      }
    }
  }
}

// ---------------- launch ----------------

extern "C" void kernel_launch(void* const* d_in, const int* in_sizes, int n_in,
                              void* d_out, int out_size, void* d_ws, size_t ws_size,
                              hipStream_t stream) {
  const float* features = (const float*)d_in[0];
  const int*   src      = (const int*)d_in[1];
  const int*   dst      = (const int*)d_in[2];
  const float* w_in     = (const float*)d_in[3];
  const float* b_in     = (const float*)d_in[4];
  const float* gc_w     = (const float*)d_in[5];
  const float* gc_b     = (const float*)d_in[6];
  const float* bn_gamma = (const float*)d_in[7];
  const float* bn_beta  = (const float*)d_in[8];
  const float* bn_mean  = (const float*)d_in[9];
  const float* bn_var   = (const float*)d_in[10];
  const float* attn_w1  = (const float*)d_in[11];
  const float* attn_b1  = (const float*)d_in[12];
  const float* attn_w2  = (const float*)d_in[13];
  const float* attn_b2  = (const float*)d_in[14];
  const float* agg_w    = (const float*)d_in[15];
  const float* agg_b    = (const float*)d_in[16];
  const float* out_w    = (const float*)d_in[17];
  const float* out_b    = (const float*)d_in[18];
  float* out = (float*)d_out;

  float* fbase = (float*)d_ws;
  float* Af = fbase;                     // NH fp32: attn 'a' (single consumer)
  float* inv_mean = fbase + NH;
  float* inv_in   = inv_mean + NN;
  float* inv_out  = inv_in + NN;
  int* indeg   = (int*)(inv_out + NN);   // NN
  int* row_ptr = indeg + NN;             // NN+16
  int* bsum    = row_ptr + NN + 16;      // 256
  int* col     = bsum + 256;             // EE
  int4* nodeinfo = (int4*)(col + EE);    // NN

  // preprocessing scratch aliased into Af (dead before Af's first write)
  unsigned* pd   = (unsigned*)Af;             // NSL*NN
  unsigned* ps   = pd + (long)NSL * NN;
  unsigned* cur0 = ps + (long)NSL * NN;

  // packed bf16 hi/lo weights
  ushort* pk = (ushort*)(nodeinfo + NN);
  const int SZ256 = 8 * 8 * 512;     // K=256, NTP=8
  const int SZ128 = 4 * 8 * 512;     // K=128, NTP=8
  const int SZOUT = 4 * 4 * 512;     // K=128, NTP=4
  ushort* win_hi = pk;  pk += SZ256;  ushort* win_lo = pk;  pk += SZ256;
  ushort* agg_hi = pk;  pk += SZ256;  ushort* agg_lo = pk;  pk += SZ256;
  ushort* at1_hi = pk;  pk += SZ256;  ushort* at1_lo = pk;  pk += SZ256;
  ushort* gch[3], *gcl[3];
  for (int i = 0; i < 3; ++i) { gch[i] = pk; pk += SZ128; gcl[i] = pk; pk += SZ128; }
  ushort* ow_hi = pk;  pk += SZOUT;   ushort* ow_lo = pk;  pk += SZOUT;

  // packed-bf16x2 activation pools + fp16 gather table
  unsigned* P0 = (unsigned*)pk;       // h0 -> rst1
  unsigned* P1 = P0 + NH;             // neigh -> spmm rst (reused)
  unsigned* P2 = P1 + NH;             // agg -> rst0 -> rst2
  __half* X16 = (__half*)(P2 + NH);   // NH halfs, sliced [2][NN][64]

  dim3 b256(256), b128(128);
  const int gN = (NN + 255) / 256;
  const int gblocks = (NN + 63) / 64;     // 782
  const int gspmm = (NN / 16) * 8;        // 25000
  const int gpre = NSL * 4;

  // graph preprocessing (no global atomics)
  count_partial_kernel<<<gpre, b256, 0, stream>>>((const int4*)dst, pd);
  count_partial_kernel<<<gpre, b256, 0, stream>>>((const int4*)src, ps);
  reduce_deg_kernel<<<gN, b256, 0, stream>>>(pd, ps, indeg, inv_mean, inv_in, inv_out);
  scan_block_kernel<<<gN, b256, 0, stream>>>(indeg, row_ptr, bsum, NN);
  scan_block_kernel<<<1, b256, 0, stream>>>(bsum, bsum, nullptr, gN);
  cursor_init_kernel<<<gN, b256, 0, stream>>>(row_ptr, bsum, pd, cur0, inv_mean, inv_in, nodeinfo);
  fill_partial_kernel<<<gpre, b256, 0, stream>>>((const int4*)dst, (const int4*)src, cur0, col);

  // weight prepack
  prepack_kernel<<<(SZ256 + 255) / 256, b256, 0, stream>>>(w_in,    HF, HF, 8, win_hi, win_lo, SZ256);
  prepack_kernel<<<(SZ256 + 255) / 256, b256, 0, stream>>>(agg_w,   HF, HF, 8, agg_hi, agg_lo, SZ256);
  prepack_kernel<<<(SZ256 + 255) / 256, b256, 0, stream>>>(attn_w1, HF, HF, 8, at1_hi, at1_lo, SZ256);
  for (int i = 0; i < 3; ++i)
    prepack_kernel<<<(SZ128 + 255) / 256, b256, 0, stream>>>(gc_w + (long)i * HF * HF, HF, HF, 8, gch[i], gcl[i], SZ128);
  prepack_kernel<<<(SZOUT + 255) / 256, b256, 0, stream>>>(out_w, CC, CC, 4, ow_hi, ow_lo, SZOUT);

  // h0 = relu(features @ w_in + b_in) -> P0 (packed) + X16 raw
  mgemm_kernel<8, 8, 8, EPI_RELU, H16_RAW, 0, 1><<<gblocks, b256, 0, stream>>>(
      features, INF_, features + 128, INF_, win_hi, win_lo, b_in,
      nullptr, nullptr, nullptr, nullptr, nullptr,
      nullptr, P0, HF, HF, X16, nullptr);
  // neigh = mean-agg(h0) -> P1
  spmm64s_kernel<<<gspmm, b256, 0, stream>>>(nodeinfo, col, X16, 0, P1);
  // agg = relu([h0|neigh] @ agg_w + agg_b) -> P2
  mgemm_kernel<8, 8, 8, EPI_RELU, H16_NONE, 1, 1><<<gblocks, b256, 0, stream>>>(
      P0, HF, P1, HF, agg_hi, agg_lo, agg_b,
      nullptr, nullptr, nullptr, nullptr, nullptr,
      nullptr, P2, HF, HF, nullptr, nullptr);
  // a = relu([h0|agg] @ attn_w1 + attn_b1) -> Af (fp32)
  mgemm_kernel<8, 8, 8, EPI_RELU, H16_NONE, 1, 0><<<gblocks, b256, 0, stream>>>(
      P0, HF, P2, HF, at1_hi, at1_lo, attn_b1,
      nullptr, nullptr, nullptr, nullptr, nullptr,
      Af, nullptr, HF, HF, nullptr, nullptr);
  // h_att = h0 + agg * sigmoid(a@w2+b2) -> X16 (scaled by inv_out)
  attn_hatt_kernel<<<NN, b128, 0, stream>>>(Af, attn_w2, attn_b2, P0, P2, inv_out, X16);

  // layer 0: spmm -> P1 ; rst0 = relu(BN(P1@gc0+b0)) -> P2 + X16
  spmm64s_kernel<<<gspmm, b256, 0, stream>>>(nodeinfo, col, X16, 1, P1);
  mgemm_kernel<4, 8, 8, EPI_BN, H16_SCALED, 1, 1><<<gblocks, b256, 0, stream>>>(
      P1, HF, nullptr, 0, gch[0], gcl[0], gc_b,
      bn_gamma, bn_beta, bn_mean, bn_var, nullptr,
      nullptr, P2, HF, HF, X16, inv_out);
  // layer 1: spmm -> P1 ; rst1 = relu(BN(P1@gc1+b1)) + rst0 -> P0 + X16
  spmm64s_kernel<<<gspmm, b256, 0, stream>>>(nodeinfo, col, X16, 1, P1);
  mgemm_kernel<4, 8, 8, EPI_BN_RES, H16_SCALED, 1, 1><<<gblocks, b256, 0, stream>>>(
      P1, HF, nullptr, 0, gch[1], gcl[1], gc_b + HF,
      bn_gamma + HF, bn_beta + HF, bn_mean + HF, bn_var + HF, P2,
      nullptr, P0, HF, HF, X16, inv_out);
  // layer 2: spmm -> P1 ; rst2 = relu(BN(P1@gc2+b2)) + rst1 -> P2
  spmm64s_kernel<<<gspmm, b256, 0, stream>>>(nodeinfo, col, X16, 1, P1);
  mgemm_kernel<4, 8, 8, EPI_BN_RES, H16_NONE, 1, 1><<<gblocks, b256, 0, stream>>>(
      P1, HF, nullptr, 0, gch[2], gcl[2], gc_b + 2 * HF,
      bn_gamma + 2 * HF, bn_beta + 2 * HF, bn_mean + 2 * HF, bn_var + 2 * HF, P0,
      nullptr, P2, HF, HF, nullptr, nullptr);

  // out = rst2 @ out_w + out_b -> d_out
  mgemm_kernel<4, 4, 4, EPI_NONE, H16_NONE, 1, 0><<<gblocks, b256, 0, stream>>>(
      P2, HF, nullptr, 0, ow_hi, ow_lo, out_b,
      nullptr, nullptr, nullptr, nullptr, nullptr,
      out, nullptr, CC, CC, nullptr, nullptr);
}

// Round 13
// 376.384 us; speedup vs baseline: 1.2496x; 1.2143x over previous
//
#include <hip/hip_runtime.h>
#include <hip/hip_fp16.h>
#include <math.h>

constexpr int NN  = 50000;   // nodes
constexpr int EE  = 800000;  // edges
constexpr int INF_ = 256;    // input feat
constexpr int HF  = 128;     // hidden
constexpr int CC  = 50;      // classes
constexpr long NH = (long)NN * HF;
constexpr int NSL = 32;          // edge slices (preprocessing)
constexpr int ESL = EE / NSL;    // 25000 edges per slice
constexpr int CHK = 12500;       // nodes per chunk (4 chunks), 50KB LDS
#define EPSV 1e-5f

enum { EPI_RELU = 0, EPI_NONE = 1, EPI_BN = 2, EPI_BN_RES = 3 };
enum { H16_NONE = 0, H16_SCALED = 2 };

typedef __attribute__((ext_vector_type(4))) float f32x4;
typedef __attribute__((ext_vector_type(8))) _Float16 f16x8;

// ---------------- graph preprocessing (atomic-free: LDS histograms) ----------------

__global__ __launch_bounds__(256) void count_partial_kernel(
    const int4* __restrict__ keys4, unsigned* __restrict__ partials) {
  __shared__ unsigned cnt[CHK];
  const int chunk = blockIdx.x & 3;
  const int sl = blockIdx.x >> 2;
  for (int i = threadIdx.x; i < CHK; i += 256) cnt[i] = 0;
  __syncthreads();
  const int base4 = sl * (ESL / 4);
  const int lo = chunk * CHK;
  for (int i = threadIdx.x; i < ESL / 4; i += 256) {
    int4 k = keys4[base4 + i];
    int a;
    a = k.x - lo; if ((unsigned)a < (unsigned)CHK) atomicAdd(&cnt[a], 1u);
    a = k.y - lo; if ((unsigned)a < (unsigned)CHK) atomicAdd(&cnt[a], 1u);
    a = k.z - lo; if ((unsigned)a < (unsigned)CHK) atomicAdd(&cnt[a], 1u);
    a = k.w - lo; if ((unsigned)a < (unsigned)CHK) atomicAdd(&cnt[a], 1u);
  }
  __syncthreads();
  unsigned* p = partials + (long)sl * NN + lo;
  for (int i = threadIdx.x; i < CHK; i += 256) p[i] = cnt[i];
}

__global__ __launch_bounds__(256) void reduce_deg_kernel(
    const unsigned* __restrict__ pd, const unsigned* __restrict__ ps,
    int* __restrict__ indeg, float* __restrict__ inv_mean,
    float* __restrict__ inv_in, float* __restrict__ inv_out) {
  int n = blockIdx.x * 256 + threadIdx.x;
  if (n >= NN) return;
  unsigned di = 0, dz = 0;
  #pragma unroll 8
  for (int sl = 0; sl < NSL; ++sl) {
    di += pd[(long)sl * NN + n];
    dz += ps[(long)sl * NN + n];
  }
  indeg[n] = (int)di;
  float fdi = fmaxf((float)di, 1.f), fdz = fmaxf((float)dz, 1.f);
  inv_mean[n] = 1.f / fdi;
  inv_in[n]  = rsqrtf(fdi);
  inv_out[n] = rsqrtf(fdz);
}

__global__ __launch_bounds__(256) void scan_block_kernel(const int* __restrict__ counts,
                                                         int* excl, int* bsum, int n) {
  __shared__ int sh[256];
  int i = blockIdx.x * 256 + threadIdx.x;
  int v = (i < n) ? counts[i] : 0;
  sh[threadIdx.x] = v;
  __syncthreads();
  #pragma unroll
  for (int off = 1; off < 256; off <<= 1) {
    int tv = (threadIdx.x >= off) ? sh[threadIdx.x - off] : 0;
    __syncthreads();
    sh[threadIdx.x] += tv;
    __syncthreads();
  }
  if (i < n) excl[i] = sh[threadIdx.x] - v;
  if (threadIdx.x == 255 && bsum) bsum[blockIdx.x] = sh[255];
}

// builds per-(slice,node) cursors AND packed nodeinfo {e0, end, inv_mean, inv_in}
__global__ void cursor_init_kernel(const int* __restrict__ row_ptr, const int* __restrict__ bsum,
                                   const unsigned* __restrict__ pd,
                                   unsigned* __restrict__ cur0,
                                   const float* __restrict__ inv_mean,
                                   const float* __restrict__ inv_in,
                                   int4* __restrict__ nodeinfo) {
  int n = blockIdx.x * 256 + threadIdx.x;
  if (n >= NN) return;
  unsigned start = (unsigned)(row_ptr[n] + bsum[n >> 8]);
  unsigned run = start;
  #pragma unroll 8
  for (int sl = 0; sl < NSL; ++sl) {
    cur0[(long)sl * NN + n] = run;
    run += pd[(long)sl * NN + n];
  }
  nodeinfo[n] = make_int4((int)start, (int)run,
                          __float_as_int(inv_mean[n]), __float_as_int(inv_in[n]));
}

__global__ __launch_bounds__(256) void fill_partial_kernel(
    const int4* __restrict__ dst4, const int4* __restrict__ src4,
    const unsigned* __restrict__ cur0, int* __restrict__ col) {
  __shared__ unsigned cur[CHK];
  const int chunk = blockIdx.x & 3;
  const int sl = blockIdx.x >> 2;
  const int lo = chunk * CHK;
  const unsigned* c0 = cur0 + (long)sl * NN + lo;
  for (int i = threadIdx.x; i < CHK; i += 256) cur[i] = c0[i];
  __syncthreads();
  const int base4 = sl * (ESL / 4);
  for (int i = threadIdx.x; i < ESL / 4; i += 256) {
    int4 d = dst4[base4 + i];
    int4 s = src4[base4 + i];
    int a;
    a = d.x - lo; if ((unsigned)a < (unsigned)CHK) col[atomicAdd(&cur[a], 1u)] = s.x;
    a = d.y - lo; if ((unsigned)a < (unsigned)CHK) col[atomicAdd(&cur[a], 1u)] = s.y;
    a = d.z - lo; if ((unsigned)a < (unsigned)CHK) col[atomicAdd(&cur[a], 1u)] = s.z;
    a = d.w - lo; if ((unsigned)a < (unsigned)CHK) col[atomicAdd(&cur[a], 1u)] = s.w;
  }
}

// ---------------- SpMM over feature-sliced fp16 table (2 slices x 64 feats) ----------------
// fp16 accumulate (8 v_pk_add_f16 per 2 edges), masks peeled to tail,
// f32 shuffle-tree reduce, fp16 output into the sliced A-pool layout.

__global__ __launch_bounds__(256) void spmm64s_kernel(
    const int4* __restrict__ nodeinfo, const int* __restrict__ cols,
    const __half* __restrict__ xs, int useW,
    __half* __restrict__ outh) {
  const int t = threadIdx.x;
  const int lane = t & 63;
  const int wv = t >> 6;
  const int b = blockIdx.x;
  const int xcd = b & 7;
  const int slice = xcd >> 2;
  const int sub = xcd & 3;
  const int node = (b >> 3) * 16 + wv * 4 + sub;   // exact cover: NN = 3125*16
  const int q8 = lane & 7;       // 16B chunk of the 128B row
  const int e8 = lane >> 3;      // edge slot within group of 8
  const __half* xb = xs + (long)slice * NN * 64 + q8 * 8;
  int4 ni = nodeinfo[node];
  const int e0 = ni.x, end = ni.y;
  const float d = __int_as_float(useW ? ni.w : ni.z);
  const __half2 z2 = __float2half2_rn(0.f);
  __half2 A0 = z2, A1 = z2, A2 = z2, A3 = z2;
  __half2 C0 = z2, C1 = z2, C2 = z2, C3 = z2;
  const int nfull = (end - e0) & ~15;
  int e = e0;
  for (; e < e0 + nfull; e += 16) {
    int s0 = cols[e + e8];
    int s1 = cols[e + 8 + e8];
    f32x4 v0 = *(const f32x4*)(xb + (unsigned)s0 * 64u);
    f32x4 v1 = *(const f32x4*)(xb + (unsigned)s1 * 64u);
    const __half2* h0 = (const __half2*)&v0;
    const __half2* h1 = (const __half2*)&v1;
    A0 = __hadd2(A0, h0[0]); A1 = __hadd2(A1, h0[1]);
    A2 = __hadd2(A2, h0[2]); A3 = __hadd2(A3, h0[3]);
    C0 = __hadd2(C0, h1[0]); C1 = __hadd2(C1, h1[1]);
    C2 = __hadd2(C2, h1[2]); C3 = __hadd2(C3, h1[3]);
  }
  if (e < end) {               // tail: <16 edges, per-lane predicated
    int ee0 = e + e8;
    if (ee0 < end) {
      int s0 = cols[ee0];
      f32x4 v0 = *(const f32x4*)(xb + (unsigned)s0 * 64u);
      const __half2* h0 = (const __half2*)&v0;
      A0 = __hadd2(A0, h0[0]); A1 = __hadd2(A1, h0[1]);
      A2 = __hadd2(A2, h0[2]); A3 = __hadd2(A3, h0[3]);
    }
    int ee1 = e + 8 + e8;
    if (ee1 < end) {
      int s1 = cols[ee1];
      f32x4 v1 = *(const f32x4*)(xb + (unsigned)s1 * 64u);
      const __half2* h1 = (const __half2*)&v1;
      C0 = __hadd2(C0, h1[0]); C1 = __hadd2(C1, h1[1]);
      C2 = __hadd2(C2, h1[2]); C3 = __hadd2(C3, h1[3]);
    }
  }
  float2 f0 = __half22float2(A0), f1 = __half22float2(A1);
  float2 f2 = __half22float2(A2), f3 = __half22float2(A3);
  float2 g0 = __half22float2(C0), g1 = __half22float2(C1);
  float2 g2 = __half22float2(C2), g3 = __half22float2(C3);
  float a0 = f0.x + g0.x, a1 = f0.y + g0.y;
  float a2 = f1.x + g1.x, a3 = f1.y + g1.y;
  float a4 = f2.x + g2.x, a5 = f2.y + g2.y;
  float a6 = f3.x + g3.x, a7 = f3.y + g3.y;
  #pragma unroll
  for (int m = 8; m < 64; m <<= 1) {
    a0 += __shfl_xor(a0, m, 64); a1 += __shfl_xor(a1, m, 64);
    a2 += __shfl_xor(a2, m, 64); a3 += __shfl_xor(a3, m, 64);
    a4 += __shfl_xor(a4, m, 64); a5 += __shfl_xor(a5, m, 64);
    a6 += __shfl_xor(a6, m, 64); a7 += __shfl_xor(a7, m, 64);
  }
  if (lane < 8) {
    union { __half h[8]; uint4 u; } o;
    o.h[0] = __float2half(a0 * d); o.h[1] = __float2half(a1 * d);
    o.h[2] = __float2half(a2 * d); o.h[3] = __float2half(a3 * d);
    o.h[4] = __float2half(a4 * d); o.h[5] = __float2half(a5 * d);
    o.h[6] = __float2half(a6 * d); o.h[7] = __float2half(a7 * d);
    *(uint4*)(outh + ((long)slice * NN + node) * 64 + q8 * 8) = o.u;
  }
}

// ---------------- attention gate + gated residual (sliced fp16 inputs) ----------------

__global__ __launch_bounds__(128) void attn_hatt_kernel(
    const float* __restrict__ a, const float* __restrict__ w2, const float* __restrict__ b2,
    const __half* __restrict__ h0t, const __half* __restrict__ aggt,
    const float* __restrict__ inv_out,
    __half* __restrict__ x16) {
  int r = blockIdx.x, f = threadIdx.x;
  float v = a[(long)r * HF + f] * w2[f];
  #pragma unroll
  for (int off = 32; off >= 1; off >>= 1) v += __shfl_down(v, off, 64);
  __shared__ float red[2];
  if ((f & 63) == 0) red[f >> 6] = v;
  __syncthreads();
  float dot = red[0] + red[1] + b2[0];
  float s = 1.f / (1.f + __expf(-dot));
  long sidx = ((long)(f >> 6) * NN + r) * 64 + (f & 63);
  float h = __half2float(h0t[sidx]) + __half2float(aggt[sidx]) * s;
  x16[sidx] = __float2half(h * inv_out[r]);
}

// ---------------- weight prepack: fp32 W[K][N] -> fp16 MFMA fragments ----------------

__global__ void prepack_kernel(const float* __restrict__ W, int N, int ldw, int NTpad,
                               ushort* __restrict__ outw, int total) {
  int idx = blockIdx.x * 256 + threadIdx.x;
  if (idx >= total) return;
  int j    = idx & 7;
  int lane = (idx >> 3) & 63;
  int rest = idx >> 9;
  int nt = rest % NTpad;
  int kc = rest / NTpad;
  int k = kc * 32 + (lane >> 4) * 8 + j;
  int n = nt * 16 + (lane & 15);
  float w = (n < N) ? W[(long)k * ldw + n] : 0.f;
  outw[idx] = __half_as_ushort(__float2half(w));
}

// ---------------- fp16 MFMA GEMM: out = epi( [A1|A2] @ W + bias ) ----------------
// Block = 64 rows x 128 cols, 4 waves; wave = 16 rows x NT*16 cols (782 blocks).
// A loads fully hoisted (KC x 16B per lane in flight) for memory-level parallelism.
// ASRC=0: A fp32 row-major (features), cvt in compute loop.
// ASRC=1: A fp16 sliced [k>>6][NN][64] (activation pool).
// OUTM=0: fp32 out (ldc). OUTM=1: fp16 sliced pool out (+scaled x16 if H16_SCALED).

template<int KC, int NT, int NTP, int EPI, int H16, int ASRC, int OUTM>
__global__ __launch_bounds__(256) void mgemm_kernel(
    const void* __restrict__ A1, int lda1,
    const void* __restrict__ A2,
    const ushort* __restrict__ Bf,
    const float* __restrict__ bias,
    const float* __restrict__ g, const float* __restrict__ be,
    const float* __restrict__ mu, const float* __restrict__ va,
    const __half* __restrict__ resp,
    float* __restrict__ outf, __half* __restrict__ outh, int ldc, int Ncols,
    __half* __restrict__ x16, const float* __restrict__ rowscale) {
  const int t = threadIdx.x;
  const int lane = t & 63;
  const int wid = t >> 6;
  const int rowbase = blockIdx.x * 64 + wid * 16;
  const int arow = rowbase + (lane & 15);
  const int kgrp = (lane >> 4) * 8;
  const bool rowok = arow < NN;

  f32x4 acc[NT];
  #pragma unroll
  for (int n = 0; n < NT; ++n) acc[n] = (f32x4){0.f, 0.f, 0.f, 0.f};

  // hoisted A loads (all KC fragments in flight)
  const f32x4 z4 = {0.f, 0.f, 0.f, 0.f};
  f32x4 fra[ASRC == 0 ? KC : 1], frb[ASRC == 0 ? KC : 1];
  uint4 areg[ASRC == 1 ? KC : 1];
  if (ASRC == 0) {
    #pragma unroll
    for (int kc = 0; kc < KC; ++kc) {
      const float* p = (const float*)A1 + (long)arow * lda1 + kc * 32 + kgrp;
      fra[kc] = rowok ? *(const f32x4*)p : z4;
      frb[kc] = rowok ? *(const f32x4*)(p + 4) : z4;
    }
  } else {
    #pragma unroll
    for (int kc = 0; kc < KC; ++kc) {
      const bool second = (KC == 8) && (kc >= 4);
      const ushort* At = (const ushort*)(second ? A2 : A1);
      int k0 = (second ? (kc - 4) : kc) * 32 + kgrp;
      const ushort* p = At + ((long)(k0 >> 6) * NN + arow) * 64 + (k0 & 63);
      areg[kc] = rowok ? *(const uint4*)p : make_uint4(0, 0, 0, 0);
    }
  }

  #pragma unroll
  for (int kc = 0; kc < KC; ++kc) {
    f16x8 av;
    if (ASRC == 0) {
      #pragma unroll
      for (int j = 0; j < 4; ++j) {
        av[j]     = (_Float16)fra[kc][j];
        av[j + 4] = (_Float16)frb[kc][j];
      }
    } else {
      union { uint4 u; f16x8 v; } cv;
      cv.u = areg[kc];
      av = cv.v;
    }
    const ushort* bp = Bf + ((long)kc * NTP * 64 + lane) * 8;
    #pragma unroll
    for (int nt = 0; nt < NT; ++nt) {
      union { uint4 u; f16x8 v; } bv;
      bv.u = *(const uint4*)(bp + (long)nt * 512);
      acc[nt] = __builtin_amdgcn_mfma_f32_16x16x32_f16(av, bv.v, acc[nt], 0, 0, 0);
    }
  }

  const int colg = lane & 15;
  const int rsub = (lane >> 4) * 4;
  #pragma unroll
  for (int nt = 0; nt < NT; ++nt) {
    int c = nt * 16 + colg;
    if (c >= Ncols) continue;
    float bb = bias ? bias[c] : 0.f;
    float scale = 1.f, shift = 0.f;
    if (EPI == EPI_BN || EPI == EPI_BN_RES) {
      scale = g[c] * rsqrtf(va[c] + EPSV);
      shift = be[c] - mu[c] * scale;
    }
    #pragma unroll
    for (int i = 0; i < 4; ++i) {
      int r = rowbase + rsub + i;
      if (r >= NN) continue;
      long sidx = ((long)(c >> 6) * NN + r) * 64 + (c & 63);
      float v = acc[nt][i] + bb;
      if (EPI == EPI_RELU) {
        v = fmaxf(v, 0.f);
      } else if (EPI == EPI_BN || EPI == EPI_BN_RES) {
        v = fmaxf(v * scale + shift, 0.f);
        if (EPI == EPI_BN_RES) v += __half2float(resp[sidx]);
      }
      if (OUTM == 0) {
        outf[(long)r * ldc + c] = v;
      } else {
        outh[sidx] = __float2half(v);
        if (H16 == H16_SCALED) x16[sidx] = __float2half(v * rowscale[r]);
      }
    }
  }
}

// ---------------- launch ----------------

extern "C" void kernel_launch(void* const* d_in, const int* in_sizes, int n_in,
                              void* d_out, int out_size, void* d_ws, size_t ws_size,
                              hipStream_t stream) {
  const float* features = (const float*)d_in[0];
  const int*   src      = (const int*)d_in[1];
  const int*   dst      = (const int*)d_in[2];
  const float* w_in     = (const float*)d_in[3];
  const float* b_in     = (const float*)d_in[4];
  const float* gc_w     = (const float*)d_in[5];
  const float* gc_b     = (const float*)d_in[6];
  const float* bn_gamma = (const float*)d_in[7];
  const float* bn_beta  = (const float*)d_in[8];
  const float* bn_mean  = (const float*)d_in[9];
  const float* bn_var   = (const float*)d_in[10];
  const float* attn_w1  = (const float*)d_in[11];
  const float* attn_b1  = (const float*)d_in[12];
  const float* attn_w2  = (const float*)d_in[13];
  const float* attn_b2  = (const float*)d_in[14];
  const float* agg_w    = (const float*)d_in[15];
  const float* agg_b    = (const float*)d_in[16];
  const float* out_w    = (const float*)d_in[17];
  const float* out_b    = (const float*)d_in[18];
  float* out = (float*)d_out;

  float* fbase = (float*)d_ws;
  float* Af = fbase;                     // NH fp32: attn 'a' (single consumer)
  float* inv_mean = fbase + NH;
  float* inv_in   = inv_mean + NN;
  float* inv_out  = inv_in + NN;
  int* indeg   = (int*)(inv_out + NN);   // NN
  int* row_ptr = indeg + NN;             // NN+16
  int* bsum    = row_ptr + NN + 16;      // 256
  int* col     = bsum + 256;             // EE
  int4* nodeinfo = (int4*)(col + EE);    // NN

  // preprocessing scratch aliased into Af (dead before Af's first write)
  unsigned* pd   = (unsigned*)Af;             // NSL*NN
  unsigned* ps   = pd + (long)NSL * NN;
  unsigned* cur0 = ps + (long)NSL * NN;

  // packed fp16 weights
  ushort* pk = (ushort*)(nodeinfo + NN);
  const int SZ256 = 8 * 8 * 512;     // K=256, NTP=8
  const int SZ128 = 4 * 8 * 512;     // K=128, NTP=8
  const int SZOUT = 4 * 4 * 512;     // K=128, NTP=4
  ushort* win_f = pk;  pk += SZ256;
  ushort* agg_f = pk;  pk += SZ256;
  ushort* at1_f = pk;  pk += SZ256;
  ushort* gcf[3];
  for (int i = 0; i < 3; ++i) { gcf[i] = pk; pk += SZ128; }
  ushort* ow_f = pk;  pk += SZOUT;

  // fp16 activation pools, sliced [2][NN][64] (GEMM-A operand == gather table)
  __half* T0 = (__half*)pk;           // h0 -> rst1
  __half* T1 = T0 + NH;               // neigh -> spmm rst (per layer)
  __half* T2 = T1 + NH;               // agg -> rst0 -> rst2
  __half* X16 = T2 + NH;              // scaled gather table (h_att / rst * inv_out)

  dim3 b256(256), b128(128);
  const int gN = (NN + 255) / 256;
  const int gblocks = (NN + 63) / 64;     // 782
  const int gspmm = (NN / 16) * 8;        // 25000
  const int gpre = NSL * 4;

  // graph preprocessing (no global atomics)
  count_partial_kernel<<<gpre, b256, 0, stream>>>((const int4*)dst, pd);
  count_partial_kernel<<<gpre, b256, 0, stream>>>((const int4*)src, ps);
  reduce_deg_kernel<<<gN, b256, 0, stream>>>(pd, ps, indeg, inv_mean, inv_in, inv_out);
  scan_block_kernel<<<gN, b256, 0, stream>>>(indeg, row_ptr, bsum, NN);
  scan_block_kernel<<<1, b256, 0, stream>>>(bsum, bsum, nullptr, gN);
  cursor_init_kernel<<<gN, b256, 0, stream>>>(row_ptr, bsum, pd, cur0, inv_mean, inv_in, nodeinfo);
  fill_partial_kernel<<<gpre, b256, 0, stream>>>((const int4*)dst, (const int4*)src, cur0, col);

  // weight prepack (fp16)
  prepack_kernel<<<(SZ256 + 255) / 256, b256, 0, stream>>>(w_in,    HF, HF, 8, win_f, SZ256);
  prepack_kernel<<<(SZ256 + 255) / 256, b256, 0, stream>>>(agg_w,   HF, HF, 8, agg_f, SZ256);
  prepack_kernel<<<(SZ256 + 255) / 256, b256, 0, stream>>>(attn_w1, HF, HF, 8, at1_f, SZ256);
  for (int i = 0; i < 3; ++i)
    prepack_kernel<<<(SZ128 + 255) / 256, b256, 0, stream>>>(gc_w + (long)i * HF * HF, HF, HF, 8, gcf[i], SZ128);
  prepack_kernel<<<(SZOUT + 255) / 256, b256, 0, stream>>>(out_w, CC, CC, 4, ow_f, SZOUT);

  // #1: h0 = relu(features @ w_in + b_in) -> T0 (fp16, doubles as gather table)
  mgemm_kernel<8, 8, 8, EPI_RELU, H16_NONE, 0, 1><<<gblocks, b256, 0, stream>>>(
      features, INF_, nullptr, win_f, b_in,
      nullptr, nullptr, nullptr, nullptr, nullptr,
      nullptr, T0, HF, HF, nullptr, nullptr);
  // spmm1: neigh = mean-agg(h0) -> T1
  spmm64s_kernel<<<gspmm, b256, 0, stream>>>(nodeinfo, col, T0, 0, T1);
  // #2: agg = relu([h0|neigh] @ agg_w + agg_b) -> T2
  mgemm_kernel<8, 8, 8, EPI_RELU, H16_NONE, 1, 1><<<gblocks, b256, 0, stream>>>(
      T0, 0, T1, agg_f, agg_b,
      nullptr, nullptr, nullptr, nullptr, nullptr,
      nullptr, T2, HF, HF, nullptr, nullptr);
  // #3: a = relu([h0|agg] @ attn_w1 + attn_b1) -> Af (fp32)
  mgemm_kernel<8, 8, 8, EPI_RELU, H16_NONE, 1, 0><<<gblocks, b256, 0, stream>>>(
      T0, 0, T2, at1_f, attn_b1,
      nullptr, nullptr, nullptr, nullptr, nullptr,
      Af, nullptr, HF, HF, nullptr, nullptr);
  // attn: h_att*inv_out -> X16
  attn_hatt_kernel<<<NN, b128, 0, stream>>>(Af, attn_w2, attn_b2, T0, T2, inv_out, X16);

  // layer 0: spmm(X16) -> T1 ; rst0 = relu(BN(T1@gc0+b0)) -> T2 (+X16 scaled)
  spmm64s_kernel<<<gspmm, b256, 0, stream>>>(nodeinfo, col, X16, 1, T1);
  mgemm_kernel<4, 8, 8, EPI_BN, H16_SCALED, 1, 1><<<gblocks, b256, 0, stream>>>(
      T1, 0, nullptr, gcf[0], gc_b,
      bn_gamma, bn_beta, bn_mean, bn_var, nullptr,
      nullptr, T2, HF, HF, X16, inv_out);
  // layer 1: spmm(X16) -> T1 ; rst1 = relu(BN(T1@gc1+b1)) + rst0 -> T0 (+X16 scaled)
  spmm64s_kernel<<<gspmm, b256, 0, stream>>>(nodeinfo, col, X16, 1, T1);
  mgemm_kernel<4, 8, 8, EPI_BN_RES, H16_SCALED, 1, 1><<<gblocks, b256, 0, stream>>>(
      T1, 0, nullptr, gcf[1], gc_b + HF,
      bn_gamma + HF, bn_beta + HF, bn_mean + HF, bn_var + HF, T2,
      nullptr, T0, HF, HF, X16, inv_out);
  // layer 2: spmm(X16) -> T1 ; rst2 = relu(BN(T1@gc2+b2)) + rst1 -> T2
  spmm64s_kernel<<<gspmm, b256, 0, stream>>>(nodeinfo, col, X16, 1, T1);
  mgemm_kernel<4, 8, 8, EPI_BN_RES, H16_NONE, 1, 1><<<gblocks, b256, 0, stream>>>(
      T1, 0, nullptr, gcf[2], gc_b + 2 * HF,
      bn_gamma + 2 * HF, bn_beta + 2 * HF, bn_mean + 2 * HF, bn_var + 2 * HF, T0,
      nullptr, T2, HF, HF, nullptr, nullptr);

  // out = rst2 @ out_w + out_b -> d_out (fp32)
  mgemm_kernel<4, 4, 4, EPI_NONE, H16_NONE, 1, 0><<<gblocks, b256, 0, stream>>>(
      T2, 0, nullptr, ow_f, out_b,
      nullptr, nullptr, nullptr, nullptr, nullptr,
      out, nullptr, CC, CC, nullptr, nullptr);
}

// Round 14
// 373.361 us; speedup vs baseline: 1.2597x; 1.0081x over previous
//
#include <hip/hip_runtime.h>
#include <hip/hip_fp16.h>
#include <math.h>

constexpr int NN  = 50000;   // nodes
constexpr int EE  = 800000;  // edges
constexpr int INF_ = 256;    // input feat
constexpr int HF  = 128;     // hidden
constexpr int CC  = 50;      // classes
constexpr long NH = (long)NN * HF;
constexpr int NSL = 32;          // edge slices (preprocessing)
constexpr int ESL = EE / NSL;    // 25000 edges per slice
constexpr int CHK = 12500;       // nodes per chunk (4 chunks), 50KB LDS
#define EPSV 1e-5f

enum { EPI_RELU = 0, EPI_NONE = 1, EPI_BN = 2, EPI_BN_RES = 3, EPI_ATTN = 4 };
enum { H16_NONE = 0, H16_SCALED = 2 };

typedef __attribute__((ext_vector_type(4))) float f32x4;
typedef __attribute__((ext_vector_type(8))) _Float16 f16x8;

// ---------------- graph preprocessing (atomic-free: LDS histograms) ----------------

// both src+dst histograms in one launch: blocks [0,128) dst, [128,256) src
__global__ __launch_bounds__(256) void count_partial2_kernel(
    const int4* __restrict__ dst4, const int4* __restrict__ src4,
    unsigned* __restrict__ pd, unsigned* __restrict__ ps) {
  __shared__ unsigned cnt[CHK];
  int bb = blockIdx.x;
  const int which = bb >> 7;
  bb &= 127;
  const int4* keys4 = which ? src4 : dst4;
  unsigned* partials = which ? ps : pd;
  const int chunk = bb & 3;
  const int sl = bb >> 2;
  for (int i = threadIdx.x; i < CHK; i += 256) cnt[i] = 0;
  __syncthreads();
  const int base4 = sl * (ESL / 4);
  const int lo = chunk * CHK;
  for (int i = threadIdx.x; i < ESL / 4; i += 256) {
    int4 k = keys4[base4 + i];
    int a;
    a = k.x - lo; if ((unsigned)a < (unsigned)CHK) atomicAdd(&cnt[a], 1u);
    a = k.y - lo; if ((unsigned)a < (unsigned)CHK) atomicAdd(&cnt[a], 1u);
    a = k.z - lo; if ((unsigned)a < (unsigned)CHK) atomicAdd(&cnt[a], 1u);
    a = k.w - lo; if ((unsigned)a < (unsigned)CHK) atomicAdd(&cnt[a], 1u);
  }
  __syncthreads();
  unsigned* p = partials + (long)sl * NN + lo;
  for (int i = threadIdx.x; i < CHK; i += 256) p[i] = cnt[i];
}

// degree reduce + inverse tables + block-level exclusive scan, in one kernel
__global__ __launch_bounds__(256) void deg_scan_kernel(
    const unsigned* __restrict__ pd, const unsigned* __restrict__ ps,
    int* __restrict__ row_ptr, int* __restrict__ bsum,
    float* __restrict__ inv_mean, float* __restrict__ inv_in,
    float* __restrict__ inv_out) {
  __shared__ int sh[256];
  int n = blockIdx.x * 256 + threadIdx.x;
  unsigned di = 0, dz = 0;
  if (n < NN) {
    #pragma unroll 8
    for (int sl = 0; sl < NSL; ++sl) {
      di += pd[(long)sl * NN + n];
      dz += ps[(long)sl * NN + n];
    }
    float fdi = fmaxf((float)di, 1.f), fdz = fmaxf((float)dz, 1.f);
    inv_mean[n] = 1.f / fdi;
    inv_in[n]  = rsqrtf(fdi);
    inv_out[n] = rsqrtf(fdz);
  }
  int v = (n < NN) ? (int)di : 0;
  sh[threadIdx.x] = v;
  __syncthreads();
  #pragma unroll
  for (int off = 1; off < 256; off <<= 1) {
    int tv = (threadIdx.x >= off) ? sh[threadIdx.x - off] : 0;
    __syncthreads();
    sh[threadIdx.x] += tv;
    __syncthreads();
  }
  if (n < NN) row_ptr[n] = sh[threadIdx.x] - v;
  if (threadIdx.x == 255) bsum[blockIdx.x] = sh[255];
}

__global__ __launch_bounds__(256) void scan_block_kernel(const int* __restrict__ counts,
                                                         int* excl, int* bsum, int n) {
  __shared__ int sh[256];
  int i = blockIdx.x * 256 + threadIdx.x;
  int v = (i < n) ? counts[i] : 0;
  sh[threadIdx.x] = v;
  __syncthreads();
  #pragma unroll
  for (int off = 1; off < 256; off <<= 1) {
    int tv = (threadIdx.x >= off) ? sh[threadIdx.x - off] : 0;
    __syncthreads();
    sh[threadIdx.x] += tv;
    __syncthreads();
  }
  if (i < n) excl[i] = sh[threadIdx.x] - v;
  if (threadIdx.x == 255 && bsum) bsum[blockIdx.x] = sh[255];
}

// per-(slice,node) cursors AND packed nodeinfo {e0, end, inv_mean, inv_in}
__global__ void cursor_init_kernel(const int* __restrict__ row_ptr, const int* __restrict__ bsum,
                                   const unsigned* __restrict__ pd,
                                   unsigned* __restrict__ cur0,
                                   const float* __restrict__ inv_mean,
                                   const float* __restrict__ inv_in,
                                   int4* __restrict__ nodeinfo) {
  int n = blockIdx.x * 256 + threadIdx.x;
  if (n >= NN) return;
  unsigned start = (unsigned)(row_ptr[n] + bsum[n >> 8]);
  unsigned run = start;
  #pragma unroll 8
  for (int sl = 0; sl < NSL; ++sl) {
    cur0[(long)sl * NN + n] = run;
    run += pd[(long)sl * NN + n];
  }
  nodeinfo[n] = make_int4((int)start, (int)run,
                          __float_as_int(inv_mean[n]), __float_as_int(inv_in[n]));
}

__global__ __launch_bounds__(256) void fill_partial_kernel(
    const int4* __restrict__ dst4, const int4* __restrict__ src4,
    const unsigned* __restrict__ cur0, int* __restrict__ col) {
  __shared__ unsigned cur[CHK];
  const int chunk = blockIdx.x & 3;
  const int sl = blockIdx.x >> 2;
  const int lo = chunk * CHK;
  const unsigned* c0 = cur0 + (long)sl * NN + lo;
  for (int i = threadIdx.x; i < CHK; i += 256) cur[i] = c0[i];
  __syncthreads();
  const int base4 = sl * (ESL / 4);
  for (int i = threadIdx.x; i < ESL / 4; i += 256) {
    int4 d = dst4[base4 + i];
    int4 s = src4[base4 + i];
    int a;
    a = d.x - lo; if ((unsigned)a < (unsigned)CHK) col[atomicAdd(&cur[a], 1u)] = s.x;
    a = d.y - lo; if ((unsigned)a < (unsigned)CHK) col[atomicAdd(&cur[a], 1u)] = s.y;
    a = d.z - lo; if ((unsigned)a < (unsigned)CHK) col[atomicAdd(&cur[a], 1u)] = s.z;
    a = d.w - lo; if ((unsigned)a < (unsigned)CHK) col[atomicAdd(&cur[a], 1u)] = s.w;
  }
}

// ---------------- SpMM over feature-sliced fp16 table (2 slices x 64 feats) ----------------
// lane = q8*8+e8 flipped: e8 = lane&7 (edge slot), q8 = lane>>3 (16B chunk).
// fp16 accumulate, register-halving butterfly over masks 4,2,1 -> final value
// at feature == lane -> fully-coalesced per-lane 2B store.

__global__ __launch_bounds__(256) void spmm64s_kernel(
    const int4* __restrict__ nodeinfo, const int* __restrict__ cols,
    const __half* __restrict__ xs, int useW,
    __half* __restrict__ outh) {
  const int t = threadIdx.x;
  const int lane = t & 63;
  const int wv = t >> 6;
  const int b = blockIdx.x;
  const int xcd = b & 7;
  const int slice = xcd >> 2;
  const int sub = xcd & 3;
  const int node = (b >> 3) * 16 + wv * 4 + sub;   // exact cover: NN = 3125*16
  const int e8 = lane & 7;       // edge slot within group of 8
  const int q8 = lane >> 3;      // 16B chunk of the 128B row
  const __half* xb = xs + (long)slice * NN * 64 + q8 * 8;
  int4 ni = nodeinfo[node];
  const int e0 = ni.x, end = ni.y;
  const float d = __int_as_float(useW ? ni.w : ni.z);
  const __half2 z2 = __float2half2_rn(0.f);
  __half2 A0 = z2, A1 = z2, A2 = z2, A3 = z2;
  __half2 C0 = z2, C1 = z2, C2 = z2, C3 = z2;
  const int nfull = (end - e0) & ~15;
  int e = e0;
  for (; e < e0 + nfull; e += 16) {
    int s0 = cols[e + e8];
    int s1 = cols[e + 8 + e8];
    f32x4 v0 = *(const f32x4*)(xb + (unsigned)s0 * 64u);
    f32x4 v1 = *(const f32x4*)(xb + (unsigned)s1 * 64u);
    const __half2* h0 = (const __half2*)&v0;
    const __half2* h1 = (const __half2*)&v1;
    A0 = __hadd2(A0, h0[0]); A1 = __hadd2(A1, h0[1]);
    A2 = __hadd2(A2, h0[2]); A3 = __hadd2(A3, h0[3]);
    C0 = __hadd2(C0, h1[0]); C1 = __hadd2(C1, h1[1]);
    C2 = __hadd2(C2, h1[2]); C3 = __hadd2(C3, h1[3]);
  }
  if (e < end) {               // tail: <16 edges, per-lane predicated
    int ee0 = e + e8;
    if (ee0 < end) {
      int s0 = cols[ee0];
      f32x4 v0 = *(const f32x4*)(xb + (unsigned)s0 * 64u);
      const __half2* h0 = (const __half2*)&v0;
      A0 = __hadd2(A0, h0[0]); A1 = __hadd2(A1, h0[1]);
      A2 = __hadd2(A2, h0[2]); A3 = __hadd2(A3, h0[3]);
    }
    int ee1 = e + 8 + e8;
    if (ee1 < end) {
      int s1 = cols[ee1];
      f32x4 v1 = *(const f32x4*)(xb + (unsigned)s1 * 64u);
      const __half2* h1 = (const __half2*)&v1;
      C0 = __hadd2(C0, h1[0]); C1 = __hadd2(C1, h1[1]);
      C2 = __hadd2(C2, h1[2]); C3 = __hadd2(C3, h1[3]);
    }
  }
  __half2 H0 = __hadd2(A0, C0), H1 = __hadd2(A1, C1);
  __half2 H2 = __hadd2(A2, C2), H3 = __hadd2(A3, C3);
  float2 p0 = __half22float2(H0), p1 = __half22float2(H1);
  float2 p2 = __half22float2(H2), p3 = __half22float2(H3);
  float f0 = p0.x, f1 = p0.y, f2 = p1.x, f3 = p1.y;
  float f4 = p2.x, f5 = p2.y, f6 = p3.x, f7 = p3.y;
  // level 1 (mask 4): keep half selected by e8 bit2
  {
    bool hi = (lane & 4) != 0;
    float t0 = hi ? f0 : f4, t1 = hi ? f1 : f5, t2 = hi ? f2 : f6, t3 = hi ? f3 : f7;
    t0 = __shfl_xor(t0, 4, 64); t1 = __shfl_xor(t1, 4, 64);
    t2 = __shfl_xor(t2, 4, 64); t3 = __shfl_xor(t3, 4, 64);
    f0 = (hi ? f4 : f0) + t0; f1 = (hi ? f5 : f1) + t1;
    f2 = (hi ? f6 : f2) + t2; f3 = (hi ? f7 : f3) + t3;
  }
  // level 2 (mask 2)
  {
    bool hi = (lane & 2) != 0;
    float t0 = hi ? f0 : f2, t1 = hi ? f1 : f3;
    t0 = __shfl_xor(t0, 2, 64); t1 = __shfl_xor(t1, 2, 64);
    f0 = (hi ? f2 : f0) + t0; f1 = (hi ? f3 : f1) + t1;
  }
  // level 3 (mask 1)
  float fin;
  {
    bool hi = (lane & 1) != 0;
    float t0 = hi ? f0 : f1;
    t0 = __shfl_xor(t0, 1, 64);
    fin = (hi ? f1 : f0) + t0;
  }
  outh[((long)slice * NN + node) * 64 + lane] = __float2half(fin * d);
}

// ---------------- fused weight prepack: all fp32 W -> fp16 MFMA fragments ----------------

constexpr int SZ256 = 8 * 8 * 512;   // K=256, NTP=8
constexpr int SZ128 = 4 * 8 * 512;   // K=128, NTP=8
constexpr int SZOUT = 4 * 4 * 512;   // K=128, NTP=4
constexpr int PK_TOTAL = 3 * SZ256 + 3 * SZ128 + SZOUT;

__global__ __launch_bounds__(256) void prepack_all_kernel(
    const float* __restrict__ w_in, const float* __restrict__ agg_w,
    const float* __restrict__ at1, const float* __restrict__ gc_w,
    const float* __restrict__ out_w, ushort* __restrict__ outbase) {
  int idx = blockIdx.x * 256 + threadIdx.x;
  if (idx >= PK_TOTAL) return;
  const float* W; int N, ldw, NTpad, local; ushort* outp;
  if (idx < 3 * SZ256) {
    int s = idx / SZ256; local = idx - s * SZ256;
    W = (s == 0) ? w_in : ((s == 1) ? agg_w : at1);
    N = HF; ldw = HF; NTpad = 8;
    outp = outbase + s * SZ256;
  } else if (idx < 3 * SZ256 + 3 * SZ128) {
    int r = idx - 3 * SZ256; int s = r / SZ128; local = r - s * SZ128;
    W = gc_w + (long)s * HF * HF; N = HF; ldw = HF; NTpad = 8;
    outp = outbase + 3 * SZ256 + s * SZ128;
  } else {
    local = idx - 3 * SZ256 - 3 * SZ128;
    W = out_w; N = CC; ldw = CC; NTpad = 4;
    outp = outbase + 3 * SZ256 + 3 * SZ128;
  }
  int j    = local & 7;
  int lane = (local >> 3) & 63;
  int rest = local >> 9;
  int nt = rest % NTpad;
  int kc = rest / NTpad;
  int k = kc * 32 + (lane >> 4) * 8 + j;
  int n = nt * 16 + (lane & 15);
  float w = (n < N) ? W[(long)k * ldw + n] : 0.f;
  outp[local] = __half_as_ushort(__float2half(w));
}

// ---------------- fp16 MFMA GEMM: out = epi( [A1|A2] @ W + bias ) ----------------
// Block = 64 rows x 128 cols, 4 waves; wave = 16 rows x NT*16 cols (782 blocks).
// A loads fully hoisted. ASRC=0: A fp32 row-major. ASRC=1: A fp16 sliced pool.
// EPI_ATTN: full attention fused in epilogue (a-dot -> sigmoid -> X16), no main out.

template<int KC, int NT, int NTP, int EPI, int H16, int ASRC, int OUTM>
__global__ __launch_bounds__(256) void mgemm_kernel(
    const void* __restrict__ A1, int lda1,
    const void* __restrict__ A2,
    const ushort* __restrict__ Bf,
    const float* __restrict__ bias,
    const float* __restrict__ g, const float* __restrict__ be,
    const float* __restrict__ mu, const float* __restrict__ va,
    const __half* __restrict__ resp,
    float* __restrict__ outf, __half* __restrict__ outh, int ldc, int Ncols,
    __half* __restrict__ x16, const float* __restrict__ rowscale) {
  const int t = threadIdx.x;
  const int lane = t & 63;
  const int wid = t >> 6;
  const int rowbase = blockIdx.x * 64 + wid * 16;
  const int arow = rowbase + (lane & 15);
  const int kgrp = (lane >> 4) * 8;
  const bool rowok = arow < NN;

  f32x4 acc[NT];
  #pragma unroll
  for (int n = 0; n < NT; ++n) acc[n] = (f32x4){0.f, 0.f, 0.f, 0.f};

  const f32x4 z4 = {0.f, 0.f, 0.f, 0.f};
  f32x4 fra[ASRC == 0 ? KC : 1], frb[ASRC == 0 ? KC : 1];
  uint4 areg[ASRC == 1 ? KC : 1];
  if (ASRC == 0) {
    #pragma unroll
    for (int kc = 0; kc < KC; ++kc) {
      const float* p = (const float*)A1 + (long)arow * lda1 + kc * 32 + kgrp;
      fra[kc] = rowok ? *(const f32x4*)p : z4;
      frb[kc] = rowok ? *(const f32x4*)(p + 4) : z4;
    }
  } else {
    #pragma unroll
    for (int kc = 0; kc < KC; ++kc) {
      const bool second = (KC == 8) && (kc >= 4);
      const ushort* At = (const ushort*)(second ? A2 : A1);
      int k0 = (second ? (kc - 4) : kc) * 32 + kgrp;
      const ushort* p = At + ((long)(k0 >> 6) * NN + arow) * 64 + (k0 & 63);
      areg[kc] = rowok ? *(const uint4*)p : make_uint4(0, 0, 0, 0);
    }
  }

  #pragma unroll
  for (int kc = 0; kc < KC; ++kc) {
    f16x8 av;
    if (ASRC == 0) {
      #pragma unroll
      for (int j = 0; j < 4; ++j) {
        av[j]     = (_Float16)fra[kc][j];
        av[j + 4] = (_Float16)frb[kc][j];
      }
    } else {
      union { uint4 u; f16x8 v; } cv;
      cv.u = areg[kc];
      av = cv.v;
    }
    const ushort* bp = Bf + ((long)kc * NTP * 64 + lane) * 8;
    #pragma unroll
    for (int nt = 0; nt < NT; ++nt) {
      union { uint4 u; f16x8 v; } bv;
      bv.u = *(const uint4*)(bp + (long)nt * 512);
      acc[nt] = __builtin_amdgcn_mfma_f32_16x16x32_f16(av, bv.v, acc[nt], 0, 0, 0);
    }
  }

  const int colg = lane & 15;
  const int rsub = (lane >> 4) * 4;

  if (EPI == EPI_ATTN) {
    // a = relu(acc + b1); dot = a . w2 per row; s = sigmoid(dot + b2)
    float part0 = 0.f, part1 = 0.f, part2 = 0.f, part3 = 0.f;
    #pragma unroll
    for (int nt = 0; nt < NT; ++nt) {
      int c = nt * 16 + colg;
      float w2v = g[c];
      float bb = bias[c];
      part0 = fmaf(fmaxf(acc[nt][0] + bb, 0.f), w2v, part0);
      part1 = fmaf(fmaxf(acc[nt][1] + bb, 0.f), w2v, part1);
      part2 = fmaf(fmaxf(acc[nt][2] + bb, 0.f), w2v, part2);
      part3 = fmaf(fmaxf(acc[nt][3] + bb, 0.f), w2v, part3);
    }
    #pragma unroll
    for (int m = 1; m <= 8; m <<= 1) {
      part0 += __shfl_xor(part0, m, 64);
      part1 += __shfl_xor(part1, m, 64);
      part2 += __shfl_xor(part2, m, 64);
      part3 += __shfl_xor(part3, m, 64);
    }
    const float b2v = be[0];
    float s0 = 1.f / (1.f + __expf(-(part0 + b2v)));
    float s1 = 1.f / (1.f + __expf(-(part1 + b2v)));
    float s2 = 1.f / (1.f + __expf(-(part2 + b2v)));
    float s3 = 1.f / (1.f + __expf(-(part3 + b2v)));
    const __half* h0t = (const __half*)A1;
    const __half* aggt = (const __half*)A2;
    #pragma unroll
    for (int nt = 0; nt < NT; ++nt) {
      int c = nt * 16 + colg;
      #pragma unroll
      for (int i = 0; i < 4; ++i) {
        int r = rowbase + rsub + i;
        if (r >= NN) continue;
        long sidx = ((long)(c >> 6) * NN + r) * 64 + (c & 63);
        float sv = (i == 0) ? s0 : ((i == 1) ? s1 : ((i == 2) ? s2 : s3));
        float h = __half2float(h0t[sidx]) + __half2float(aggt[sidx]) * sv;
        x16[sidx] = __float2half(h * rowscale[r]);
      }
    }
    return;
  }

  #pragma unroll
  for (int nt = 0; nt < NT; ++nt) {
    int c = nt * 16 + colg;
    if (c >= Ncols) continue;
    float bb = bias ? bias[c] : 0.f;
    float scale = 1.f, shift = 0.f;
    if (EPI == EPI_BN || EPI == EPI_BN_RES) {
      scale = g[c] * rsqrtf(va[c] + EPSV);
      shift = be[c] - mu[c] * scale;
    }
    #pragma unroll
    for (int i = 0; i < 4; ++i) {
      int r = rowbase + rsub + i;
      if (r >= NN) continue;
      long sidx = ((long)(c >> 6) * NN + r) * 64 + (c & 63);
      float v = acc[nt][i] + bb;
      if (EPI == EPI_RELU) {
        v = fmaxf(v, 0.f);
      } else if (EPI == EPI_BN || EPI == EPI_BN_RES) {
        v = fmaxf(v * scale + shift, 0.f);
        if (EPI == EPI_BN_RES) v += __half2float(resp[sidx]);
      }
      if (OUTM == 0) {
        outf[(long)r * ldc + c] = v;
      } else {
        outh[sidx] = __float2half(v);
        if (H16 == H16_SCALED) x16[sidx] = __float2half(v * rowscale[r]);
      }
    }
  }
}

// ---------------- launch ----------------

extern "C" void kernel_launch(void* const* d_in, const int* in_sizes, int n_in,
                              void* d_out, int out_size, void* d_ws, size_t ws_size,
                              hipStream_t stream) {
  const float* features = (const float*)d_in[0];
  const int*   src      = (const int*)d_in[1];
  const int*   dst      = (const int*)d_in[2];
  const float* w_in     = (const float*)d_in[3];
  const float* b_in     = (const float*)d_in[4];
  const float* gc_w     = (const float*)d_in[5];
  const float* gc_b     = (const float*)d_in[6];
  const float* bn_gamma = (const float*)d_in[7];
  const float* bn_beta  = (const float*)d_in[8];
  const float* bn_mean  = (const float*)d_in[9];
  const float* bn_var   = (const float*)d_in[10];
  const float* attn_w1  = (const float*)d_in[11];
  const float* attn_b1  = (const float*)d_in[12];
  const float* attn_w2  = (const float*)d_in[13];
  const float* attn_b2  = (const float*)d_in[14];
  const float* agg_w    = (const float*)d_in[15];
  const float* agg_b    = (const float*)d_in[16];
  const float* out_w    = (const float*)d_in[17];
  const float* out_b    = (const float*)d_in[18];
  float* out = (float*)d_out;

  float* fbase = (float*)d_ws;
  float* inv_mean = fbase;
  float* inv_in   = inv_mean + NN;
  float* inv_out  = inv_in + NN;
  int* row_ptr = (int*)(inv_out + NN);   // NN+16
  int* bsum    = row_ptr + NN + 16;      // 256
  int* col     = bsum + 256;             // EE
  int4* nodeinfo = (int4*)(col + EE);    // NN

  // packed fp16 weights (contiguous: win, agg, at1, gc0..2, ow)
  ushort* pk = (ushort*)(nodeinfo + NN);
  ushort* win_f = pk;
  ushort* agg_f = pk + SZ256;
  ushort* at1_f = pk + 2 * SZ256;
  ushort* gcf0  = pk + 3 * SZ256;
  ushort* gcf1  = gcf0 + SZ128;
  ushort* gcf2  = gcf1 + SZ128;
  ushort* ow_f  = gcf2 + SZ128;

  // fp16 activation pools, sliced [2][NN][64]
  __half* T0 = (__half*)(ow_f + SZOUT);  // h0 -> rst1
  __half* T1 = T0 + NH;                  // neigh / spmm rst
  __half* T2 = T1 + NH;                  // agg -> rst0 -> rst2
  __half* X16 = T2 + NH;                 // scaled gather table

  // preprocessing scratch aliased into T0/T1 (dead before their first writes)
  unsigned* pd   = (unsigned*)T0;              // NSL*NN
  unsigned* ps   = pd + (long)NSL * NN;
  unsigned* cur0 = ps + (long)NSL * NN;

  dim3 b256(256);
  const int gN = (NN + 255) / 256;
  const int gblocks = (NN + 63) / 64;     // 782
  const int gspmm = (NN / 16) * 8;        // 25000
  const int gpre = NSL * 4;

  // graph preprocessing (no global atomics)
  count_partial2_kernel<<<2 * gpre, b256, 0, stream>>>(
      (const int4*)dst, (const int4*)src, pd, ps);
  deg_scan_kernel<<<gN, b256, 0, stream>>>(pd, ps, row_ptr, bsum, inv_mean, inv_in, inv_out);
  scan_block_kernel<<<1, b256, 0, stream>>>(bsum, bsum, nullptr, gN);
  cursor_init_kernel<<<gN, b256, 0, stream>>>(row_ptr, bsum, pd, cur0, inv_mean, inv_in, nodeinfo);
  fill_partial_kernel<<<gpre, b256, 0, stream>>>((const int4*)dst, (const int4*)src, cur0, col);

  // all weight prepack in one launch
  prepack_all_kernel<<<(PK_TOTAL + 255) / 256, b256, 0, stream>>>(
      w_in, agg_w, attn_w1, gc_w, out_w, pk);

  // #1: h0 = relu(features @ w_in + b_in) -> T0
  mgemm_kernel<8, 8, 8, EPI_RELU, H16_NONE, 0, 1><<<gblocks, b256, 0, stream>>>(
      features, INF_, nullptr, win_f, b_in,
      nullptr, nullptr, nullptr, nullptr, nullptr,
      nullptr, T0, HF, HF, nullptr, nullptr);
  // spmm1: neigh = mean-agg(h0) -> T1
  spmm64s_kernel<<<gspmm, b256, 0, stream>>>(nodeinfo, col, T0, 0, T1);
  // #2: agg = relu([h0|neigh] @ agg_w + agg_b) -> T2
  mgemm_kernel<8, 8, 8, EPI_RELU, H16_NONE, 1, 1><<<gblocks, b256, 0, stream>>>(
      T0, 0, T1, agg_f, agg_b,
      nullptr, nullptr, nullptr, nullptr, nullptr,
      nullptr, T2, HF, HF, nullptr, nullptr);
  // #3 (fused attn): a = relu([h0|agg]@w1+b1); s = sigmoid(a@w2+b2);
  //                  X16 = (h0 + agg*s) * inv_out
  mgemm_kernel<8, 8, 8, EPI_ATTN, H16_NONE, 1, 1><<<gblocks, b256, 0, stream>>>(
      T0, 0, T2, at1_f, attn_b1,
      attn_w2, attn_b2, nullptr, nullptr, nullptr,
      nullptr, nullptr, HF, HF, X16, inv_out);

  // layer 0: spmm(X16) -> T1 ; rst0 = relu(BN(T1@gc0+b0)) -> T2 (+X16 scaled)
  spmm64s_kernel<<<gspmm, b256, 0, stream>>>(nodeinfo, col, X16, 1, T1);
  mgemm_kernel<4, 8, 8, EPI_BN, H16_SCALED, 1, 1><<<gblocks, b256, 0, stream>>>(
      T1, 0, nullptr, gcf0, gc_b,
      bn_gamma, bn_beta, bn_mean, bn_var, nullptr,
      nullptr, T2, HF, HF, X16, inv_out);
  // layer 1: spmm(X16) -> T1 ; rst1 = relu(BN(T1@gc1+b1)) + rst0 -> T0 (+X16 scaled)
  spmm64s_kernel<<<gspmm, b256, 0, stream>>>(nodeinfo, col, X16, 1, T1);
  mgemm_kernel<4, 8, 8, EPI_BN_RES, H16_SCALED, 1, 1><<<gblocks, b256, 0, stream>>>(
      T1, 0, nullptr, gcf1, gc_b + HF,
      bn_gamma + HF, bn_beta + HF, bn_mean + HF, bn_var + HF, T2,
      nullptr, T0, HF, HF, X16, inv_out);
  // layer 2: spmm(X16) -> T1 ; rst2 = relu(BN(T1@gc2+b2)) + rst1 -> T2
  spmm64s_kernel<<<gspmm, b256, 0, stream>>>(nodeinfo, col, X16, 1, T1);
  mgemm_kernel<4, 8, 8, EPI_BN_RES, H16_NONE, 1, 1><<<gblocks, b256, 0, stream>>>(
      T1, 0, nullptr, gcf2, gc_b + 2 * HF,
      bn_gamma + 2 * HF, bn_beta + 2 * HF, bn_mean + 2 * HF, bn_var + 2 * HF, T0,
      nullptr, T2, HF, HF, nullptr, nullptr);

  // out = rst2 @ out_w + out_b -> d_out (fp32)
  mgemm_kernel<4, 4, 4, EPI_NONE, H16_NONE, 1, 0><<<gblocks, b256, 0, stream>>>(
      T2, 0, nullptr, ow_f, out_b,
      nullptr, nullptr, nullptr, nullptr, nullptr,
      out, nullptr, CC, CC, nullptr, nullptr);
}